// Round 1
// baseline (1601.295 us; speedup 1.0000x reference)
//
#include <hip/hip_runtime.h>
#include <cstdint>

#define S_LEN 2048
#define DMODEL 1024
#define NHEADS 16
#define DK 64
#define BATCH 2

// ---------------------------------------------------------------------------
// GEMM: C = A[M,K] @ W[K,N] + bias[N]     (fp32, 64x64 tile, BK=16, 256 thr)
// HEAD_SPLIT: write C in [B, H, S, DK] layout instead of flat [M, N].
// ---------------------------------------------------------------------------
template<bool HEAD_SPLIT>
__global__ __launch_bounds__(256)
void gemm_bias_kernel(const float* __restrict__ A, const float* __restrict__ W,
                      const float* __restrict__ bias, float* __restrict__ C,
                      int M, int N, int K)
{
    __shared__ __align__(16) float As[16][68];   // transposed A tile [k][m]
    __shared__ __align__(16) float Bs[16][68];   // B tile [k][n]

    const int t  = threadIdx.x;
    const int tx = t & 15;         // 0..15 -> 4 output cols each
    const int ty = t >> 4;         // 0..15 -> 4 output rows each
    const int m0 = blockIdx.y * 64;
    const int n0 = blockIdx.x * 64;

    // staging indices
    const int ar = t >> 2;         // A row 0..63
    const int ac = (t & 3) * 4;    // A col 0,4,8,12
    const int bk = t >> 4;         // B row 0..15
    const int bc = (t & 15) * 4;   // B col 0..60

    float acc[4][4] = {};

    for (int k0 = 0; k0 < K; k0 += 16) {
        __syncthreads();
        // A tile 64x16, stored transposed
        float4 av = *(const float4*)(A + (size_t)(m0 + ar) * K + k0 + ac);
        As[ac + 0][ar] = av.x;
        As[ac + 1][ar] = av.y;
        As[ac + 2][ar] = av.z;
        As[ac + 3][ar] = av.w;
        // B tile 16x64
        *(float4*)&Bs[bk][bc] = *(const float4*)(W + (size_t)(k0 + bk) * N + n0 + bc);
        __syncthreads();

        #pragma unroll
        for (int k = 0; k < 16; ++k) {
            float4 a = *(const float4*)&As[k][ty * 4];
            float4 b = *(const float4*)&Bs[k][tx * 4];
            float aa[4] = {a.x, a.y, a.z, a.w};
            float bb[4] = {b.x, b.y, b.z, b.w};
            #pragma unroll
            for (int i = 0; i < 4; ++i)
                #pragma unroll
                for (int j = 0; j < 4; ++j)
                    acc[i][j] = fmaf(aa[i], bb[j], acc[i][j]);
        }
    }

    // epilogue: bias + store
    float4 bv = *(const float4*)(bias + n0 + tx * 4);
    #pragma unroll
    for (int i = 0; i < 4; ++i) {
        const int gm = m0 + ty * 4 + i;
        float4 r;
        r.x = acc[i][0] + bv.x;
        r.y = acc[i][1] + bv.y;
        r.z = acc[i][2] + bv.z;
        r.w = acc[i][3] + bv.w;
        if (HEAD_SPLIT) {
            const int gn = n0 + tx * 4;      // h = gn>>6 constant over the 4 cols
            const int b  = gm >> 11;         // /2048
            const int s  = gm & 2047;
            const int h  = gn >> 6;
            const int dk = gn & 63;
            float* dst = C + (((size_t)(b * NHEADS + h) * S_LEN + s) * DK) + dk;
            *(float4*)dst = r;
        } else {
            *(float4*)(C + (size_t)gm * N + n0 + tx * 4) = r;
        }
    }
}

// ---------------------------------------------------------------------------
// Flash attention (fp32). Q,K,V in [B*H, S, DK] layout. ctx out flat
// [B, S, DMODEL]. Block = 256 threads = 16 teams x 16 lanes; each team owns
// one q row; lane j computes score vs K row j of the tile and accumulates
// 4 output dims (lane*4 .. lane*4+3).
// ---------------------------------------------------------------------------
__global__ __launch_bounds__(256)
void attn_kernel(const float* __restrict__ Q, const float* __restrict__ K,
                 const float* __restrict__ V, float* __restrict__ ctx)
{
    __shared__ __align__(16) float Ks[16][68];
    __shared__ __align__(16) float Vs[16][68];

    const int t    = threadIdx.x;
    const int lane = t & 15;
    const int team = t >> 4;       // q row within block (also staging row)
    const int bh   = blockIdx.y;
    const int q0   = blockIdx.x * 16;

    // q row into registers, pre-scaled by 1/sqrt(DK)
    const float* Qrow = Q + ((size_t)bh * S_LEN + q0 + team) * DK;
    float4 q[16];
    #pragma unroll
    for (int i = 0; i < 16; ++i) {
        float4 v = *(const float4*)(Qrow + i * 4);
        v.x *= 0.125f; v.y *= 0.125f; v.z *= 0.125f; v.w *= 0.125f;
        q[i] = v;
    }

    float  m = -1e30f, l = 0.f;
    float4 o = {0.f, 0.f, 0.f, 0.f};

    const int sc = lane * 4;
    const float* Kb = K + (size_t)bh * S_LEN * DK;
    const float* Vb = V + (size_t)bh * S_LEN * DK;

    for (int k0 = 0; k0 < S_LEN; k0 += 16) {
        __syncthreads();
        *(float4*)&Ks[team][sc] = *(const float4*)(Kb + (size_t)(k0 + team) * DK + sc);
        *(float4*)&Vs[team][sc] = *(const float4*)(Vb + (size_t)(k0 + team) * DK + sc);
        __syncthreads();

        // score: q_row . K[lane]
        float s = 0.f;
        #pragma unroll
        for (int d = 0; d < 16; ++d) {
            float4 kv = *(const float4*)&Ks[lane][d * 4];
            s = fmaf(q[d].x, kv.x, s);
            s = fmaf(q[d].y, kv.y, s);
            s = fmaf(q[d].z, kv.z, s);
            s = fmaf(q[d].w, kv.w, s);
        }

        // team-wide max
        float mt = s;
        #pragma unroll
        for (int off = 8; off; off >>= 1)
            mt = fmaxf(mt, __shfl_xor(mt, off, 16));

        const float m_new = fmaxf(m, mt);
        const float corr  = __expf(m - m_new);
        const float p     = __expf(s - m_new);

        float ps = p;
        #pragma unroll
        for (int off = 8; off; off >>= 1)
            ps += __shfl_xor(ps, off, 16);

        l = l * corr + ps;
        m = m_new;
        o.x *= corr; o.y *= corr; o.z *= corr; o.w *= corr;

        #pragma unroll
        for (int j = 0; j < 16; ++j) {
            const float pj = __shfl(p, j, 16);
            float4 vv = *(const float4*)&Vs[j][lane * 4];
            o.x = fmaf(pj, vv.x, o.x);
            o.y = fmaf(pj, vv.y, o.y);
            o.z = fmaf(pj, vv.z, o.z);
            o.w = fmaf(pj, vv.w, o.w);
        }
    }

    const float inv_l = 1.f / l;
    o.x *= inv_l; o.y *= inv_l; o.z *= inv_l; o.w *= inv_l;

    // ctx[b, s, h*64 + dk]
    const int b = bh >> 4;
    const int h = bh & 15;
    float* dst = ctx + ((size_t)b * S_LEN + q0 + team) * DMODEL + h * DK + lane * 4;
    *(float4*)dst = o;
}

// ---------------------------------------------------------------------------
extern "C" void kernel_launch(void* const* d_in, const int* in_sizes, int n_in,
                              void* d_out, int out_size, void* d_ws, size_t ws_size,
                              hipStream_t stream)
{
    const float* query  = (const float*)d_in[0];
    const float* key_in = (const float*)d_in[1];
    const float* value  = (const float*)d_in[2];
    const float* w_q = (const float*)d_in[3];
    const float* b_q = (const float*)d_in[4];
    const float* w_k = (const float*)d_in[5];
    const float* b_k = (const float*)d_in[6];
    const float* w_v = (const float*)d_in[7];
    const float* b_v = (const float*)d_in[8];
    const float* w_o = (const float*)d_in[9];
    const float* b_o = (const float*)d_in[10];
    float* out = (float*)d_out;

    const int M = BATCH * S_LEN;            // 4096
    const size_t elems = (size_t)M * DMODEL;

    float* Qh  = (float*)d_ws;              // [B,H,S,DK]
    float* Kh  = Qh + elems;
    float* Vh  = Kh + elems;
    float* ctx = Vh + elems;                // [B,S,DMODEL]

    dim3 blk(256);
    dim3 grd(DMODEL / 64, M / 64);

    hipLaunchKernelGGL((gemm_bias_kernel<true>),  grd, blk, 0, stream,
                       query,  w_q, b_q, Qh,  M, DMODEL, DMODEL);
    hipLaunchKernelGGL((gemm_bias_kernel<true>),  grd, blk, 0, stream,
                       key_in, w_k, b_k, Kh,  M, DMODEL, DMODEL);
    hipLaunchKernelGGL((gemm_bias_kernel<true>),  grd, blk, 0, stream,
                       value,  w_v, b_v, Vh,  M, DMODEL, DMODEL);

    dim3 agrd(S_LEN / 16, BATCH * NHEADS);
    hipLaunchKernelGGL(attn_kernel, agrd, blk, 0, stream, Qh, Kh, Vh, ctx);

    hipLaunchKernelGGL((gemm_bias_kernel<false>), grd, blk, 0, stream,
                       ctx, w_o, b_o, out, M, DMODEL, DMODEL);
}

// Round 2
// 704.679 us; speedup vs baseline: 2.2724x; 2.2724x over previous
//
#include <hip/hip_runtime.h>
#include <cstdint>

#define S_LEN 2048
#define DMODEL 1024
#define NHEADS 16
#define DK 64
#define BATCH 2

typedef __attribute__((ext_vector_type(8))) short short8;   // 8 bf16 = 4 VGPRs
typedef __attribute__((ext_vector_type(4))) float f32x4;

__device__ __forceinline__ ushort f2bf(float f) {
    union { float f; uint32_t u; } v; v.f = f;
    uint32_t r = (v.u + 0x7fffu + ((v.u >> 16) & 1u)) >> 16;
    return (ushort)r;
}

// ---------------------------------------------------------------------------
// GEMM: C = A[M,K] @ W[K,N] + bias, fp32 compute (64x64 tile, BK=16, 256 thr)
// MODE 0: fp32 flat [M][N]
// MODE 1: bf16 head-split [B,H,S,DK], values scaled by oscale
// MODE 2: bf16 head-split TRANSPOSED [B,H,DK,S]
// ---------------------------------------------------------------------------
template<int MODE>
__global__ __launch_bounds__(256)
void gemm_bias_kernel(const float* __restrict__ A, const float* __restrict__ W,
                      const float* __restrict__ bias, void* __restrict__ Cout,
                      int M, int N, int K, float oscale)
{
    __shared__ __align__(16) float As[16][68];   // transposed A tile [k][m]
    __shared__ __align__(16) float Bs[16][68];   // B tile [k][n]

    const int t  = threadIdx.x;
    const int tx = t & 15;
    const int ty = t >> 4;
    const int m0 = blockIdx.y * 64;
    const int n0 = blockIdx.x * 64;

    const int ar = t >> 2;
    const int ac = (t & 3) * 4;
    const int bk = t >> 4;
    const int bc = (t & 15) * 4;

    float acc[4][4] = {};

    for (int k0 = 0; k0 < K; k0 += 16) {
        __syncthreads();
        float4 av = *(const float4*)(A + (size_t)(m0 + ar) * K + k0 + ac);
        As[ac + 0][ar] = av.x;
        As[ac + 1][ar] = av.y;
        As[ac + 2][ar] = av.z;
        As[ac + 3][ar] = av.w;
        *(float4*)&Bs[bk][bc] = *(const float4*)(W + (size_t)(k0 + bk) * N + n0 + bc);
        __syncthreads();

        #pragma unroll
        for (int k = 0; k < 16; ++k) {
            float4 a = *(const float4*)&As[k][ty * 4];
            float4 b = *(const float4*)&Bs[k][tx * 4];
            float aa[4] = {a.x, a.y, a.z, a.w};
            float bb[4] = {b.x, b.y, b.z, b.w};
            #pragma unroll
            for (int i = 0; i < 4; ++i)
                #pragma unroll
                for (int j = 0; j < 4; ++j)
                    acc[i][j] = fmaf(aa[i], bb[j], acc[i][j]);
        }
    }

    float4 bv = *(const float4*)(bias + n0 + tx * 4);
    #pragma unroll
    for (int i = 0; i < 4; ++i) {
        const int gm = m0 + ty * 4 + i;
        float r[4];
        r[0] = (acc[i][0] + bv.x) * oscale;
        r[1] = (acc[i][1] + bv.y) * oscale;
        r[2] = (acc[i][2] + bv.z) * oscale;
        r[3] = (acc[i][3] + bv.w) * oscale;
        const int gn  = n0 + tx * 4;
        if (MODE == 0) {
            float4 rr = {r[0], r[1], r[2], r[3]};
            *(float4*)((float*)Cout + (size_t)gm * N + gn) = rr;
        } else {
            const int b  = gm >> 11;
            const int s  = gm & 2047;
            const int h  = gn >> 6;
            const int dk = gn & 63;
            if (MODE == 1) {
                ushort4 hh;
                hh.x = f2bf(r[0]); hh.y = f2bf(r[1]);
                hh.z = f2bf(r[2]); hh.w = f2bf(r[3]);
                ushort* dst = (ushort*)Cout +
                              (((size_t)(b * NHEADS + h) * S_LEN + s) * DK) + dk;
                *(ushort4*)dst = hh;
            } else { // MODE 2: [B,H,DK,S]
                ushort* base = (ushort*)Cout +
                               ((size_t)(b * NHEADS + h) * DK) * S_LEN;
                #pragma unroll
                for (int jj = 0; jj < 4; ++jj)
                    base[(size_t)(dk + jj) * S_LEN + s] = f2bf(r[jj]);
            }
        }
    }
}

// ---------------------------------------------------------------------------
// Flash attention, bf16 MFMA (16x16x32).
// Qh, Kh: [BH][S][64] bf16 (Q pre-scaled by 0.125*log2(e)); Vt: [BH][64][S] bf16.
// ctx out: fp32 [B][S][DMODEL].
// Block = 256 = 4 waves; each wave owns 16 q rows, loops over kv tiles of 32.
// Swapped QK^T (S^T = K*Q^T) so all global fragments are contiguous 16B loads.
// ---------------------------------------------------------------------------
__global__ __launch_bounds__(256)
void attn_mfma_kernel(const ushort* __restrict__ Qh, const ushort* __restrict__ Kh,
                      const ushort* __restrict__ Vt, float* __restrict__ ctx)
{
    __shared__ __align__(16) ushort Plds[4][16][40];  // per-wave P[q][key], pad 40

    const int t    = threadIdx.x;
    const int wv   = t >> 6;
    const int lane = t & 63;
    const int c    = lane & 15;     // q-col (scores) / q-row (P A-frag)
    const int g    = lane >> 4;     // lane group 0..3
    const int bh   = blockIdx.y;
    const int q0   = blockIdx.x * 64 + wv * 16;

    const ushort* Qb = Qh + ((size_t)bh * S_LEN + q0) * DK;
    const ushort* Kb = Kh + (size_t)bh * S_LEN * DK;
    const ushort* Vb = Vt + (size_t)bh * DK * S_LEN;

    // Q fragments (B-operand): element (g,i) -> Q[q=c][h*32 + g*8 + i]
    short8 qf[2];
    qf[0] = *(const short8*)(Qb + c * DK + 0  + g * 8);
    qf[1] = *(const short8*)(Qb + c * DK + 32 + g * 8);

    float m = -3.0e38f, l = 0.f;
    f32x4 acc_o[4] = {{0,0,0,0},{0,0,0,0},{0,0,0,0},{0,0,0,0}};

    for (int k0 = 0; k0 < S_LEN; k0 += 32) {
        // ---- scores: S^T[key][q] = K . Q^T, 2 key-blocks x 2 d-halves ----
        f32x4 sa[2] = {{0,0,0,0},{0,0,0,0}};
        #pragma unroll
        for (int kb = 0; kb < 2; ++kb) {
            #pragma unroll
            for (int h = 0; h < 2; ++h) {
                short8 kf = *(const short8*)(Kb + (size_t)(k0 + kb * 16 + c) * DK
                                             + h * 32 + g * 8);
                sa[kb] = __builtin_amdgcn_mfma_f32_16x16x32_bf16(kf, qf[h], sa[kb], 0, 0, 0);
            }
        }
        // lane holds 8 scores for q=c, keys kb*16 + g*4 + j

        // ---- online softmax (stats per q=c, replicated across groups) ----
        float mt = sa[0][0];
        #pragma unroll
        for (int i = 1; i < 4; ++i) mt = fmaxf(mt, sa[0][i]);
        #pragma unroll
        for (int i = 0; i < 4; ++i) mt = fmaxf(mt, sa[1][i]);
        mt = fmaxf(mt, __shfl_xor(mt, 16));
        mt = fmaxf(mt, __shfl_xor(mt, 32));

        const float mnew = fmaxf(m, mt);
        const float corr = __builtin_amdgcn_exp2f(m - mnew);

        float p[8];
        float ps = 0.f;
        #pragma unroll
        for (int kb = 0; kb < 2; ++kb)
            #pragma unroll
            for (int i = 0; i < 4; ++i) {
                float pp = __builtin_amdgcn_exp2f(sa[kb][i] - mnew);
                p[kb * 4 + i] = pp;
                ps += pp;
            }
        ps += __shfl_xor(ps, 16);
        ps += __shfl_xor(ps, 32);
        l = l * corr + ps;
        m = mnew;

        // ---- P -> bf16 -> per-wave LDS [q=c][key] ----
        ushort4 w0, w1;
        w0.x = f2bf(p[0]); w0.y = f2bf(p[1]); w0.z = f2bf(p[2]); w0.w = f2bf(p[3]);
        w1.x = f2bf(p[4]); w1.y = f2bf(p[5]); w1.z = f2bf(p[6]); w1.w = f2bf(p[7]);
        *(ushort4*)&Plds[wv][c][g * 4]      = w0;   // keys  g*4+j
        *(ushort4*)&Plds[wv][c][16 + g * 4] = w1;   // keys 16+g*4+j

        // P A-fragment: element (g,i) -> P[q=c][key g*8+i]
        short8 pa = *(const short8*)&Plds[wv][c][g * 8];

        // ---- O rescale factors per O-row q' = g*4+j ----
        float corrj[4];
        #pragma unroll
        for (int j = 0; j < 4; ++j)
            corrj[j] = __shfl(corr, (lane & 48) | (g * 4 + j));

        // ---- PV: O[q][d] += P * V, 4 d-blocks ----
        #pragma unroll
        for (int db = 0; db < 4; ++db) {
            short8 vf = *(const short8*)(Vb + (size_t)(db * 16 + c) * S_LEN + k0 + g * 8);
            #pragma unroll
            for (int j = 0; j < 4; ++j) acc_o[db][j] *= corrj[j];
            acc_o[db] = __builtin_amdgcn_mfma_f32_16x16x32_bf16(pa, vf, acc_o[db], 0, 0, 0);
        }
    }

    // ---- epilogue: divide by l, store ctx[b, s, h*64 + d] ----
    float invj[4];
    #pragma unroll
    for (int j = 0; j < 4; ++j) {
        float lj = __shfl(l, (lane & 48) | (g * 4 + j));
        invj[j] = 1.f / lj;
    }
    const int b = bh >> 4;
    const int h = bh & 15;
    #pragma unroll
    for (int db = 0; db < 4; ++db) {
        #pragma unroll
        for (int j = 0; j < 4; ++j) {
            const int row = q0 + g * 4 + j;
            const int col = h * DK + db * 16 + c;
            ctx[((size_t)b * S_LEN + row) * DMODEL + col] = acc_o[db][j] * invj[j];
        }
    }
}

// ---------------------------------------------------------------------------
extern "C" void kernel_launch(void* const* d_in, const int* in_sizes, int n_in,
                              void* d_out, int out_size, void* d_ws, size_t ws_size,
                              hipStream_t stream)
{
    const float* query  = (const float*)d_in[0];
    const float* key_in = (const float*)d_in[1];
    const float* value  = (const float*)d_in[2];
    const float* w_q = (const float*)d_in[3];
    const float* b_q = (const float*)d_in[4];
    const float* w_k = (const float*)d_in[5];
    const float* b_k = (const float*)d_in[6];
    const float* w_v = (const float*)d_in[7];
    const float* b_v = (const float*)d_in[8];
    const float* w_o = (const float*)d_in[9];
    const float* b_o = (const float*)d_in[10];
    float* out = (float*)d_out;

    const int M = BATCH * S_LEN;                 // 4096
    const size_t elems = (size_t)M * DMODEL;     // 4M

    ushort* Qh  = (ushort*)d_ws;                 // bf16 [B,H,S,DK]
    ushort* Kh  = Qh + elems;
    ushort* Vt  = Kh + elems;                    // bf16 [B,H,DK,S]
    float*  ctx = (float*)(Vt + elems);          // fp32 [B,S,DMODEL]

    dim3 blk(256);
    dim3 grd(DMODEL / 64, M / 64);

    const float qscale = 0.125f * 1.44269504088896340736f;  // 1/sqrt(DK) * log2(e)

    hipLaunchKernelGGL((gemm_bias_kernel<1>), grd, blk, 0, stream,
                       query,  w_q, b_q, (void*)Qh, M, DMODEL, DMODEL, qscale);
    hipLaunchKernelGGL((gemm_bias_kernel<1>), grd, blk, 0, stream,
                       key_in, w_k, b_k, (void*)Kh, M, DMODEL, DMODEL, 1.0f);
    hipLaunchKernelGGL((gemm_bias_kernel<2>), grd, blk, 0, stream,
                       value,  w_v, b_v, (void*)Vt, M, DMODEL, DMODEL, 1.0f);

    dim3 agrd(S_LEN / 64, BATCH * NHEADS);
    hipLaunchKernelGGL(attn_mfma_kernel, agrd, blk, 0, stream, Qh, Kh, Vt, ctx);

    hipLaunchKernelGGL((gemm_bias_kernel<0>), grd, blk, 0, stream,
                       ctx, w_o, b_o, (void*)out, M, DMODEL, DMODEL, 1.0f);
}

// Round 3
// 192.869 us; speedup vs baseline: 8.3025x; 3.6537x over previous
//
#include <hip/hip_runtime.h>
#include <cstdint>

#define S_LEN 2048
#define DMODEL 1024
#define NHEADS 16
#define DK 64
#define BATCH 2
#define M_TOT 4096

typedef __attribute__((ext_vector_type(8))) short  short8;   // 8 bf16 = 4 VGPRs
typedef __attribute__((ext_vector_type(4))) float  f32x4;

__device__ __forceinline__ ushort f2bf(float f) {
    union { float f; uint32_t u; } v; v.f = f;
    uint32_t r = (v.u + 0x7fffu + ((v.u >> 16) & 1u)) >> 16;
    return (ushort)r;
}
__device__ __forceinline__ float bf2f(ushort u) {
    union { uint32_t u; float f; } v; v.u = ((uint32_t)u) << 16;
    return v.f;
}

__device__ __forceinline__ void gl_lds16(const void* g, void* l) {
    __builtin_amdgcn_global_load_lds(
        (const __attribute__((address_space(1))) void*)(g),
        (__attribute__((address_space(3))) void*)(l), 16, 0, 0);
}

// ---------------------------------------------------------------------------
// fp32 -> bf16 row-major converter (8 elems/thread)
// ---------------------------------------------------------------------------
__global__ __launch_bounds__(256)
void conv_bf16_kernel(const float* __restrict__ in, ushort* __restrict__ out, int n8)
{
    int i = blockIdx.x * 256 + threadIdx.x;
    const int stride = gridDim.x * 256;
    for (; i < n8; i += stride) {
        const float4* p = (const float4*)(in + (size_t)i * 8);
        float4 a = p[0], b = p[1];
        ushort r[8];
        r[0]=f2bf(a.x); r[1]=f2bf(a.y); r[2]=f2bf(a.z); r[3]=f2bf(a.w);
        r[4]=f2bf(b.x); r[5]=f2bf(b.y); r[6]=f2bf(b.z); r[7]=f2bf(b.w);
        *(ushort4*)(out + (size_t)i * 8)     = *(ushort4*)&r[0];
        *(ushort4*)(out + (size_t)i * 8 + 4) = *(ushort4*)&r[4];
    }
}

// ---------------------------------------------------------------------------
// W[k][n] fp32 -> Wt[n][k] bf16 (hi, optional lo).  64x64 tiles.
// ---------------------------------------------------------------------------
template<bool LO>
__global__ __launch_bounds__(256)
void wtrans_kernel(const float* __restrict__ w, ushort* __restrict__ hi,
                   ushort* __restrict__ lo)
{
    __shared__ float t[64][65];
    const int n0 = blockIdx.x * 64, k0 = blockIdx.y * 64;
    const int r  = threadIdx.x >> 2;        // 0..63
    const int cb = (threadIdx.x & 3) * 16;  // 0,16,32,48

    #pragma unroll
    for (int j = 0; j < 4; ++j) {
        float4 v = *(const float4*)(w + (size_t)(k0 + r) * DMODEL + n0 + cb + j * 4);
        t[r][cb + j*4 + 0] = v.x;
        t[r][cb + j*4 + 1] = v.y;
        t[r][cb + j*4 + 2] = v.z;
        t[r][cb + j*4 + 3] = v.w;
    }
    __syncthreads();

    ushort h8[16], l8[16];
    #pragma unroll
    for (int j = 0; j < 16; ++j) {
        float x = t[cb + j][r];             // = w[k0+cb+j][n0+r]
        ushort h = f2bf(x);
        h8[j] = h;
        if (LO) l8[j] = f2bf(x - bf2f(h));
    }
    ushort* dsth = hi + (size_t)(n0 + r) * DMODEL + k0 + cb;
    *(ushort4*)(dsth + 0)  = *(ushort4*)&h8[0];
    *(ushort4*)(dsth + 4)  = *(ushort4*)&h8[4];
    *(ushort4*)(dsth + 8)  = *(ushort4*)&h8[8];
    *(ushort4*)(dsth + 12) = *(ushort4*)&h8[12];
    if (LO) {
        ushort* dstl = lo + (size_t)(n0 + r) * DMODEL + k0 + cb;
        *(ushort4*)(dstl + 0)  = *(ushort4*)&l8[0];
        *(ushort4*)(dstl + 4)  = *(ushort4*)&l8[4];
        *(ushort4*)(dstl + 8)  = *(ushort4*)&l8[8];
        *(ushort4*)(dstl + 12) = *(ushort4*)&l8[12];
    }
}

// ---------------------------------------------------------------------------
// bf16 MFMA GEMM:  C = A[M][1024] @ Wt[n][k]^T + bias
// BM=128 BN=64 BK=64, 256 thr = 4 waves (2x2), wave tile 64x32, dbuf LDS.
// OMODE 1: bf16 head-split [B,H,S,DK] * oscale;  OMODE 2: bf16 [B,H,DK,S].
// ---------------------------------------------------------------------------
template<int OMODE>
__global__ __launch_bounds__(256)
void gemm_bf16_kernel(const ushort* __restrict__ A, const ushort* __restrict__ Bt,
                      const float* __restrict__ bias, ushort* __restrict__ out,
                      float oscale)
{
    __shared__ __align__(16) ushort lds[2][12288];   // 2 x (128+64)*64 bf16 = 2x24KB

    const int t = threadIdx.x, wv = t >> 6, lane = t & 63;
    const int c = lane & 15, g = lane >> 4;
    const int m0 = blockIdx.y * 128, n0 = blockIdx.x * 64;
    const int wr = wv >> 1, wc = wv & 1;
    const int lrow = lane >> 3, lcol = lane & 7;

    f32x4 acc[4][2];
    #pragma unroll
    for (int i = 0; i < 4; ++i)
        #pragma unroll
        for (int j = 0; j < 2; ++j)
            acc[i][j] = (f32x4){0.f, 0.f, 0.f, 0.f};

    auto stage = [&](int buf, int kt) {
        #pragma unroll
        for (int j = 0; j < 6; ++j) {
            const int ci = wv * 6 + j;
            ushort* dst = &lds[buf][ci * 512];
            const ushort* src;
            if (ci < 16) {                     // A rows ci*8..+7
                const int row  = ci * 8 + lrow;
                const int colb = (lcol * 16) ^ ((row & 7) << 4);
                src = A + (size_t)(m0 + row) * 1024 + kt * 64 + (colb >> 1);
            } else {                           // B rows (n-major)
                const int row  = (ci - 16) * 8 + lrow;
                const int colb = (lcol * 16) ^ ((row & 7) << 4);
                src = Bt + (size_t)(n0 + row) * 1024 + kt * 64 + (colb >> 1);
            }
            gl_lds16(src, dst);
        }
    };

    stage(0, 0);
    __syncthreads();

    for (int kt = 0; kt < 16; ++kt) {
        const int cur = kt & 1;
        if (kt < 15) stage(cur ^ 1, kt + 1);

        const char* la = (const char*)&lds[cur][0];
        const char* lb = (const char*)&lds[cur][8192];
        #pragma unroll
        for (int kk = 0; kk < 2; ++kk) {
            short8 af[4], bf[2];
            #pragma unroll
            for (int mf = 0; mf < 4; ++mf) {
                const int row = wr * 64 + mf * 16 + c;
                af[mf] = *(const short8*)(la + row * 128 +
                          ((kk * 64 + g * 16) ^ ((c & 7) << 4)));
            }
            #pragma unroll
            for (int nf = 0; nf < 2; ++nf) {
                const int row = wc * 32 + nf * 16 + c;
                bf[nf] = *(const short8*)(lb + row * 128 +
                          ((kk * 64 + g * 16) ^ ((c & 7) << 4)));
            }
            #pragma unroll
            for (int mf = 0; mf < 4; ++mf)
                #pragma unroll
                for (int nf = 0; nf < 2; ++nf)
                    acc[mf][nf] = __builtin_amdgcn_mfma_f32_16x16x32_bf16(
                        af[mf], bf[nf], acc[mf][nf], 0, 0, 0);
        }
        __syncthreads();
    }

    // epilogue
    const int b      = m0 >> 11;
    const int s_base = m0 & 2047;
    #pragma unroll
    for (int nf = 0; nf < 2; ++nf) {
        const int ncol = n0 + wc * 32 + nf * 16 + c;
        const float bv = bias[ncol];
        const int h = ncol >> 6, dk = ncol & 63;
        #pragma unroll
        for (int mf = 0; mf < 4; ++mf) {
            if (OMODE == 1) {
                #pragma unroll
                for (int j = 0; j < 4; ++j) {
                    const int s = s_base + wr * 64 + mf * 16 + g * 4 + j;
                    out[(((size_t)(b * NHEADS + h) * S_LEN + s) * DK) + dk] =
                        f2bf((acc[mf][nf][j] + bv) * oscale);
                }
            } else {                           // OMODE 2: [B,H,DK,S]
                ushort4 v4;
                v4.x = f2bf((acc[mf][nf][0] + bv) * oscale);
                v4.y = f2bf((acc[mf][nf][1] + bv) * oscale);
                v4.z = f2bf((acc[mf][nf][2] + bv) * oscale);
                v4.w = f2bf((acc[mf][nf][3] + bv) * oscale);
                const int s = s_base + wr * 64 + mf * 16 + g * 4;
                *(ushort4*)&out[((size_t)(b * NHEADS + h) * DK + dk) * S_LEN + s] = v4;
            }
        }
    }
}

// ---------------------------------------------------------------------------
// Split (hi/lo) bf16 GEMM for O-projection: out fp32 = A @ Wt^T + bias.
// 3-term: Ahi*Whi + Ahi*Wlo + Alo*Whi. Single-buffered 48KB LDS.
// ---------------------------------------------------------------------------
__global__ __launch_bounds__(256)
void gemm_split_kernel(const ushort* __restrict__ Ahi, const ushort* __restrict__ Alo,
                       const ushort* __restrict__ Bhi, const ushort* __restrict__ Blo,
                       const float* __restrict__ bias, float* __restrict__ out)
{
    __shared__ __align__(16) ushort lds[24576];   // Ahi 16K | Alo 16K | Bhi 8K | Blo 8K bytes

    const int t = threadIdx.x, wv = t >> 6, lane = t & 63;
    const int c = lane & 15, g = lane >> 4;
    const int m0 = blockIdx.y * 128, n0 = blockIdx.x * 64;
    const int wr = wv >> 1, wc = wv & 1;
    const int lrow = lane >> 3, lcol = lane & 7;

    f32x4 acc[4][2];
    #pragma unroll
    for (int i = 0; i < 4; ++i)
        #pragma unroll
        for (int j = 0; j < 2; ++j)
            acc[i][j] = (f32x4){0.f, 0.f, 0.f, 0.f};

    for (int kt = 0; kt < 16; ++kt) {
        if (kt) __syncthreads();
        #pragma unroll
        for (int j = 0; j < 12; ++j) {
            const int ci = wv * 12 + j;
            ushort* dst = &lds[ci * 512];
            const ushort* src;
            int row, colb;
            if (ci < 16) {
                row = ci * 8 + lrow; colb = (lcol*16) ^ ((row&7)<<4);
                src = Ahi + (size_t)(m0+row)*1024 + kt*64 + (colb>>1);
            } else if (ci < 32) {
                row = (ci-16)*8 + lrow; colb = (lcol*16) ^ ((row&7)<<4);
                src = Alo + (size_t)(m0+row)*1024 + kt*64 + (colb>>1);
            } else if (ci < 40) {
                row = (ci-32)*8 + lrow; colb = (lcol*16) ^ ((row&7)<<4);
                src = Bhi + (size_t)(n0+row)*1024 + kt*64 + (colb>>1);
            } else {
                row = (ci-40)*8 + lrow; colb = (lcol*16) ^ ((row&7)<<4);
                src = Blo + (size_t)(n0+row)*1024 + kt*64 + (colb>>1);
            }
            gl_lds16(src, dst);
        }
        __syncthreads();

        const char* lah = (const char*)&lds[0];
        const char* lal = (const char*)&lds[8192];
        const char* lbh = (const char*)&lds[16384];
        const char* lbl = (const char*)&lds[20480];
        #pragma unroll
        for (int kk = 0; kk < 2; ++kk) {
            short8 ah[4], al[4], bh[2], bl[2];
            #pragma unroll
            for (int mf = 0; mf < 4; ++mf) {
                const int row = wr*64 + mf*16 + c;
                const int off = row*128 + ((kk*64 + g*16) ^ ((c&7)<<4));
                ah[mf] = *(const short8*)(lah + off);
                al[mf] = *(const short8*)(lal + off);
            }
            #pragma unroll
            for (int nf = 0; nf < 2; ++nf) {
                const int row = wc*32 + nf*16 + c;
                const int off = row*128 + ((kk*64 + g*16) ^ ((c&7)<<4));
                bh[nf] = *(const short8*)(lbh + off);
                bl[nf] = *(const short8*)(lbl + off);
            }
            #pragma unroll
            for (int mf = 0; mf < 4; ++mf)
                #pragma unroll
                for (int nf = 0; nf < 2; ++nf) {
                    acc[mf][nf] = __builtin_amdgcn_mfma_f32_16x16x32_bf16(ah[mf], bh[nf], acc[mf][nf], 0,0,0);
                    acc[mf][nf] = __builtin_amdgcn_mfma_f32_16x16x32_bf16(ah[mf], bl[nf], acc[mf][nf], 0,0,0);
                    acc[mf][nf] = __builtin_amdgcn_mfma_f32_16x16x32_bf16(al[mf], bh[nf], acc[mf][nf], 0,0,0);
                }
        }
    }

    #pragma unroll
    for (int nf = 0; nf < 2; ++nf) {
        const int ncol = n0 + wc*32 + nf*16 + c;
        const float bv = bias[ncol];
        #pragma unroll
        for (int mf = 0; mf < 4; ++mf)
            #pragma unroll
            for (int j = 0; j < 4; ++j) {
                const int m = m0 + wr*64 + mf*16 + g*4 + j;
                out[(size_t)m * 1024 + ncol] = acc[mf][nf][j] + bv;
            }
    }
}

// ---------------------------------------------------------------------------
// Flash attention, bf16 MFMA, block-shared LDS K/V tiles (64 keys), dbuf.
// Qh,Kh: [BH][S][64] bf16 (Q pre-scaled by log2e/8); Vt: [BH][64][S] bf16.
// Out: ctx hi/lo bf16 [B][S][DMODEL].  256 thr = 4 waves, each 16 q rows.
// ---------------------------------------------------------------------------
__global__ __launch_bounds__(256)
void attn_kernel2(const ushort* __restrict__ Qh, const ushort* __restrict__ Kh,
                  const ushort* __restrict__ Vt, ushort* __restrict__ ctx_hi,
                  ushort* __restrict__ ctx_lo)
{
    __shared__ __align__(16) ushort KV[2][8192];      // [buf][K 4096 | V 4096]
    __shared__ __align__(16) ushort Plds[4][16][72];

    const int t = threadIdx.x, wv = t >> 6, lane = t & 63;
    const int c = lane & 15, g = lane >> 4;
    const int bh = blockIdx.y;
    const int q0 = blockIdx.x * 64 + wv * 16;
    const int lrow = lane >> 3, lcol = lane & 7;

    const ushort* Kb = Kh + (size_t)bh * S_LEN * DK;
    const ushort* Vb = Vt + (size_t)bh * DK * S_LEN;

    const ushort* Qb = Qh + ((size_t)bh * S_LEN + q0 + c) * DK;
    short8 qf[2];
    qf[0] = *(const short8*)(Qb + g * 8);
    qf[1] = *(const short8*)(Qb + 32 + g * 8);

    auto stage = [&](int buf, int k0) {
        #pragma unroll
        for (int j = 0; j < 4; ++j) {
            const int ci = wv * 4 + j;
            ushort* dst = &KV[buf][ci * 512];
            const ushort* src;
            if (ci < 8) {                  // K tile rows = key
                const int row  = ci * 8 + lrow;
                const int colb = (lcol * 16) ^ ((row & 7) << 4);
                src = Kb + (size_t)(k0 + row) * DK + (colb >> 1);
            } else {                       // V tile rows = d
                const int row  = (ci - 8) * 8 + lrow;
                const int colb = (lcol * 16) ^ ((row & 7) << 4);
                src = Vb + (size_t)row * S_LEN + k0 + (colb >> 1);
            }
            gl_lds16(src, dst);
        }
    };

    float m = -3.0e38f, l = 0.f;
    f32x4 acc_o[4];
    #pragma unroll
    for (int i = 0; i < 4; ++i) acc_o[i] = (f32x4){0.f, 0.f, 0.f, 0.f};

    stage(0, 0);
    __syncthreads();

    for (int kt = 0; kt < 32; ++kt) {
        const int cur = kt & 1;
        if (kt < 31) stage(cur ^ 1, (kt + 1) * 64);

        const char* Kl = (const char*)&KV[cur][0];
        const char* Vl = (const char*)&KV[cur][4096];

        // ---- QK^T swapped: sa[kb] lane(c,g) reg j = S[key kb*16+g*4+j][q=c]
        f32x4 sa[4];
        #pragma unroll
        for (int kb = 0; kb < 4; ++kb) sa[kb] = (f32x4){0.f,0.f,0.f,0.f};
        #pragma unroll
        for (int kb = 0; kb < 4; ++kb) {
            const int row = kb * 16 + c;
            #pragma unroll
            for (int h = 0; h < 2; ++h) {
                short8 kf = *(const short8*)(Kl + row * 128 +
                             ((h * 64 + g * 16) ^ ((c & 7) << 4)));
                sa[kb] = __builtin_amdgcn_mfma_f32_16x16x32_bf16(kf, qf[h], sa[kb], 0,0,0);
            }
        }

        // ---- online softmax over 16 lane-local + cross-g reduce ----
        float mt = sa[0][0];
        #pragma unroll
        for (int kb = 0; kb < 4; ++kb)
            #pragma unroll
            for (int j = 0; j < 4; ++j) mt = fmaxf(mt, sa[kb][j]);
        mt = fmaxf(mt, __shfl_xor(mt, 16));
        mt = fmaxf(mt, __shfl_xor(mt, 32));

        const float mnew = fmaxf(m, mt);
        const float corr = __builtin_amdgcn_exp2f(m - mnew);

        float p[16], ps = 0.f;
        #pragma unroll
        for (int kb = 0; kb < 4; ++kb)
            #pragma unroll
            for (int j = 0; j < 4; ++j) {
                float pp = __builtin_amdgcn_exp2f(sa[kb][j] - mnew);
                p[kb * 4 + j] = pp;
                ps += pp;
            }
        ps += __shfl_xor(ps, 16);
        ps += __shfl_xor(ps, 32);
        l = l * corr + ps;
        m = mnew;

        // ---- P -> bf16 -> per-wave LDS [q=c][key] ----
        #pragma unroll
        for (int kb = 0; kb < 4; ++kb) {
            ushort4 w4;
            w4.x = f2bf(p[kb*4+0]); w4.y = f2bf(p[kb*4+1]);
            w4.z = f2bf(p[kb*4+2]); w4.w = f2bf(p[kb*4+3]);
            *(ushort4*)&Plds[wv][c][kb * 16 + g * 4] = w4;
        }
        short8 pa0 = *(const short8*)&Plds[wv][c][g * 8];
        short8 pa1 = *(const short8*)&Plds[wv][c][32 + g * 8];

        float corrj[4];
        #pragma unroll
        for (int j = 0; j < 4; ++j)
            corrj[j] = __shfl(corr, (lane & 48) | (g * 4 + j));

        // ---- PV ----
        #pragma unroll
        for (int db = 0; db < 4; ++db) {
            const int row = db * 16 + c;
            short8 vf0 = *(const short8*)(Vl + row * 128 +
                          ((g * 16)      ^ ((c & 7) << 4)));
            short8 vf1 = *(const short8*)(Vl + row * 128 +
                          ((64 + g * 16) ^ ((c & 7) << 4)));
            #pragma unroll
            for (int j = 0; j < 4; ++j) acc_o[db][j] *= corrj[j];
            acc_o[db] = __builtin_amdgcn_mfma_f32_16x16x32_bf16(pa0, vf0, acc_o[db], 0,0,0);
            acc_o[db] = __builtin_amdgcn_mfma_f32_16x16x32_bf16(pa1, vf1, acc_o[db], 0,0,0);
        }
        __syncthreads();
    }

    // ---- epilogue: /l, write ctx hi/lo bf16 ----
    float invj[4];
    #pragma unroll
    for (int j = 0; j < 4; ++j)
        invj[j] = 1.f / __shfl(l, (lane & 48) | (g * 4 + j));

    const int b = bh >> 4, h = bh & 15;
    #pragma unroll
    for (int db = 0; db < 4; ++db)
        #pragma unroll
        for (int j = 0; j < 4; ++j) {
            const float val = acc_o[db][j] * invj[j];
            const ushort hi = f2bf(val);
            const ushort lo = f2bf(val - bf2f(hi));
            const size_t idx = ((size_t)b * S_LEN + q0 + g * 4 + j) * DMODEL
                             + h * DK + db * 16 + c;
            ctx_hi[idx] = hi;
            ctx_lo[idx] = lo;
        }
}

// ---------------------------------------------------------------------------
extern "C" void kernel_launch(void* const* d_in, const int* in_sizes, int n_in,
                              void* d_out, int out_size, void* d_ws, size_t ws_size,
                              hipStream_t stream)
{
    const float* query  = (const float*)d_in[0];
    const float* key_in = (const float*)d_in[1];
    const float* value  = (const float*)d_in[2];
    const float* w_q = (const float*)d_in[3];
    const float* b_q = (const float*)d_in[4];
    const float* w_k = (const float*)d_in[5];
    const float* b_k = (const float*)d_in[6];
    const float* w_v = (const float*)d_in[7];
    const float* b_v = (const float*)d_in[8];
    const float* w_o = (const float*)d_in[9];
    const float* b_o = (const float*)d_in[10];
    float* out = (float*)d_out;

    const size_t E4M = (size_t)M_TOT * DMODEL;   // 4M elems
    const size_t E1M = (size_t)DMODEL * DMODEL;  // 1M elems

    ushort* ws = (ushort*)d_ws;
    ushort* Aq    = ws;                // 4M  (later aliased as ctx_hi)
    ushort* Ak    = Aq + E4M;          // 4M  (later aliased as ctx_lo)
    ushort* Av    = Ak + E4M;          // 4M
    ushort* Qh    = Av + E4M;          // 4M
    ushort* Kh    = Qh + E4M;          // 4M
    ushort* Vt    = Kh + E4M;          // 4M
    ushort* Wq    = Vt + E4M;          // 1M
    ushort* Wk    = Wq + E1M;
    ushort* Wv    = Wk + E1M;
    ushort* Wo_hi = Wv + E1M;
    ushort* Wo_lo = Wo_hi + E1M;       // total 29M ushorts = 58 MB
    ushort* ctx_hi = Aq;
    ushort* ctx_lo = Ak;

    const float qscale = 0.125f * 1.44269504088896340736f;

    dim3 blk(256);
    // conversions
    hipLaunchKernelGGL(conv_bf16_kernel, dim3(2048), blk, 0, stream, query,  Aq, (int)(E4M/8));
    hipLaunchKernelGGL(conv_bf16_kernel, dim3(2048), blk, 0, stream, key_in, Ak, (int)(E4M/8));
    hipLaunchKernelGGL(conv_bf16_kernel, dim3(2048), blk, 0, stream, value,  Av, (int)(E4M/8));
    hipLaunchKernelGGL((wtrans_kernel<false>), dim3(16,16), blk, 0, stream, w_q, Wq, (ushort*)nullptr);
    hipLaunchKernelGGL((wtrans_kernel<false>), dim3(16,16), blk, 0, stream, w_k, Wk, (ushort*)nullptr);
    hipLaunchKernelGGL((wtrans_kernel<false>), dim3(16,16), blk, 0, stream, w_v, Wv, (ushort*)nullptr);
    hipLaunchKernelGGL((wtrans_kernel<true>),  dim3(16,16), blk, 0, stream, w_o, Wo_hi, Wo_lo);

    // projections
    dim3 ggrd(DMODEL / 64, M_TOT / 128);
    hipLaunchKernelGGL((gemm_bf16_kernel<1>), ggrd, blk, 0, stream, Aq, Wq, b_q, Qh, qscale);
    hipLaunchKernelGGL((gemm_bf16_kernel<1>), ggrd, blk, 0, stream, Ak, Wk, b_k, Kh, 1.0f);
    hipLaunchKernelGGL((gemm_bf16_kernel<2>), ggrd, blk, 0, stream, Av, Wv, b_v, Vt, 1.0f);

    // attention
    dim3 agrd(S_LEN / 64, BATCH * NHEADS);
    hipLaunchKernelGGL(attn_kernel2, agrd, blk, 0, stream, Qh, Kh, Vt, ctx_hi, ctx_lo);

    // output projection (split precision)
    hipLaunchKernelGGL(gemm_split_kernel, ggrd, blk, 0, stream,
                       ctx_hi, ctx_lo, Wo_hi, Wo_lo, b_o, out);
}

// Round 4
// 160.069 us; speedup vs baseline: 10.0038x; 1.2049x over previous
//
#include <hip/hip_runtime.h>
#include <cstdint>

#define S_LEN 2048
#define DMODEL 1024
#define NHEADS 16
#define DK 64
#define BATCH 2
#define M_TOT 4096

typedef __attribute__((ext_vector_type(8))) short  short8;   // 8 bf16 = 4 VGPRs
typedef __attribute__((ext_vector_type(4))) float  f32x4;

__device__ __forceinline__ ushort f2bf(float f) {
    union { float f; uint32_t u; } v; v.f = f;
    uint32_t r = (v.u + 0x7fffu + ((v.u >> 16) & 1u)) >> 16;
    return (ushort)r;
}
__device__ __forceinline__ float bf2f(ushort u) {
    union { uint32_t u; float f; } v; v.u = ((uint32_t)u) << 16;
    return v.f;
}

__device__ __forceinline__ void gl_lds16(const void* g, void* l) {
    __builtin_amdgcn_global_load_lds(
        (const __attribute__((address_space(1))) void*)(g),
        (__attribute__((address_space(3))) void*)(l), 16, 0, 0);
}

// ---------------------------------------------------------------------------
// fused fp32 -> bf16 converter for q,k,v (blockIdx.z picks tensor)
// ---------------------------------------------------------------------------
__global__ __launch_bounds__(256)
void conv3_kernel(const float* __restrict__ a0, const float* __restrict__ a1,
                  const float* __restrict__ a2, ushort* __restrict__ o0,
                  ushort* __restrict__ o1, ushort* __restrict__ o2, int n8)
{
    const float*  in  = blockIdx.z == 0 ? a0 : (blockIdx.z == 1 ? a1 : a2);
    ushort*       out = blockIdx.z == 0 ? o0 : (blockIdx.z == 1 ? o1 : o2);
    int i = blockIdx.x * 256 + threadIdx.x;
    const int stride = gridDim.x * 256;
    for (; i < n8; i += stride) {
        const float4* p = (const float4*)(in + (size_t)i * 8);
        float4 a = p[0], b = p[1];
        ushort r[8];
        r[0]=f2bf(a.x); r[1]=f2bf(a.y); r[2]=f2bf(a.z); r[3]=f2bf(a.w);
        r[4]=f2bf(b.x); r[5]=f2bf(b.y); r[6]=f2bf(b.z); r[7]=f2bf(b.w);
        *(ushort4*)(out + (size_t)i * 8)     = *(ushort4*)&r[0];
        *(ushort4*)(out + (size_t)i * 8 + 4) = *(ushort4*)&r[4];
    }
}

// ---------------------------------------------------------------------------
// fused W[k][n] fp32 -> Wt[n][k] bf16 for w_q,w_k,w_v (blockIdx.z picks)
// ---------------------------------------------------------------------------
__global__ __launch_bounds__(256)
void wtrans3_kernel(const float* __restrict__ wq, const float* __restrict__ wk,
                    const float* __restrict__ wv, ushort* __restrict__ oq,
                    ushort* __restrict__ ok, ushort* __restrict__ ov)
{
    const float* w  = blockIdx.z == 0 ? wq : (blockIdx.z == 1 ? wk : wv);
    ushort*      hi = blockIdx.z == 0 ? oq : (blockIdx.z == 1 ? ok : ov);

    __shared__ float t[64][65];
    const int n0 = blockIdx.x * 64, k0 = blockIdx.y * 64;
    const int r  = threadIdx.x >> 2;
    const int cb = (threadIdx.x & 3) * 16;

    #pragma unroll
    for (int j = 0; j < 4; ++j) {
        float4 v = *(const float4*)(w + (size_t)(k0 + r) * DMODEL + n0 + cb + j * 4);
        t[r][cb + j*4 + 0] = v.x;
        t[r][cb + j*4 + 1] = v.y;
        t[r][cb + j*4 + 2] = v.z;
        t[r][cb + j*4 + 3] = v.w;
    }
    __syncthreads();

    ushort h8[16];
    #pragma unroll
    for (int j = 0; j < 16; ++j) h8[j] = f2bf(t[cb + j][r]);
    ushort* dsth = hi + (size_t)(n0 + r) * DMODEL + k0 + cb;
    *(ushort4*)(dsth + 0)  = *(ushort4*)&h8[0];
    *(ushort4*)(dsth + 4)  = *(ushort4*)&h8[4];
    *(ushort4*)(dsth + 8)  = *(ushort4*)&h8[8];
    *(ushort4*)(dsth + 12) = *(ushort4*)&h8[12];
}

// w_o: hi + lo split
__global__ __launch_bounds__(256)
void wtrans_o_kernel(const float* __restrict__ w, ushort* __restrict__ hi,
                     ushort* __restrict__ lo)
{
    __shared__ float t[64][65];
    const int n0 = blockIdx.x * 64, k0 = blockIdx.y * 64;
    const int r  = threadIdx.x >> 2;
    const int cb = (threadIdx.x & 3) * 16;

    #pragma unroll
    for (int j = 0; j < 4; ++j) {
        float4 v = *(const float4*)(w + (size_t)(k0 + r) * DMODEL + n0 + cb + j * 4);
        t[r][cb + j*4 + 0] = v.x;
        t[r][cb + j*4 + 1] = v.y;
        t[r][cb + j*4 + 2] = v.z;
        t[r][cb + j*4 + 3] = v.w;
    }
    __syncthreads();

    ushort h8[16], l8[16];
    #pragma unroll
    for (int j = 0; j < 16; ++j) {
        float x = t[cb + j][r];
        ushort h = f2bf(x);
        h8[j] = h;
        l8[j] = f2bf(x - bf2f(h));
    }
    ushort* dsth = hi + (size_t)(n0 + r) * DMODEL + k0 + cb;
    ushort* dstl = lo + (size_t)(n0 + r) * DMODEL + k0 + cb;
    #pragma unroll
    for (int j = 0; j < 4; ++j) {
        *(ushort4*)(dsth + j*4) = *(ushort4*)&h8[j*4];
        *(ushort4*)(dstl + j*4) = *(ushort4*)&l8[j*4];
    }
}

// ---------------------------------------------------------------------------
// bf16 MFMA GEMM:  C = A[M][1024] @ Wt[n][k]^T + bias
// BM=128 BN=64 BK=64, 256 thr = 4 waves (2x2), wave tile 64x32, dbuf LDS.
// OMODE 1: bf16 head-split [B,H,S,DK] * oscale;  OMODE 2: bf16 [B,H,DK,S].
// ---------------------------------------------------------------------------
template<int OMODE>
__global__ __launch_bounds__(256)
void gemm_bf16_kernel(const ushort* __restrict__ A, const ushort* __restrict__ Bt,
                      const float* __restrict__ bias, ushort* __restrict__ out,
                      float oscale)
{
    __shared__ __align__(16) ushort lds[2][12288];   // 2 x (128+64)*64 bf16

    const int t = threadIdx.x, wv = t >> 6, lane = t & 63;
    const int c = lane & 15, g = lane >> 4;
    const int m0 = blockIdx.y * 128, n0 = blockIdx.x * 64;
    const int wr = wv >> 1, wc = wv & 1;
    const int lrow = lane >> 3, lcol = lane & 7;

    f32x4 acc[4][2];
    #pragma unroll
    for (int i = 0; i < 4; ++i)
        #pragma unroll
        for (int j = 0; j < 2; ++j)
            acc[i][j] = (f32x4){0.f, 0.f, 0.f, 0.f};

    auto stage = [&](int buf, int kt) {
        #pragma unroll
        for (int j = 0; j < 6; ++j) {
            const int ci = wv * 6 + j;
            ushort* dst = &lds[buf][ci * 512];
            const ushort* src;
            if (ci < 16) {
                const int row  = ci * 8 + lrow;
                const int colb = (lcol * 16) ^ ((row & 7) << 4);
                src = A + (size_t)(m0 + row) * 1024 + kt * 64 + (colb >> 1);
            } else {
                const int row  = (ci - 16) * 8 + lrow;
                const int colb = (lcol * 16) ^ ((row & 7) << 4);
                src = Bt + (size_t)(n0 + row) * 1024 + kt * 64 + (colb >> 1);
            }
            gl_lds16(src, dst);
        }
    };

    stage(0, 0);
    __syncthreads();

    for (int kt = 0; kt < 16; ++kt) {
        const int cur = kt & 1;
        if (kt < 15) stage(cur ^ 1, kt + 1);

        const char* la = (const char*)&lds[cur][0];
        const char* lb = (const char*)&lds[cur][8192];
        #pragma unroll
        for (int kk = 0; kk < 2; ++kk) {
            short8 af[4], bf[2];
            #pragma unroll
            for (int mf = 0; mf < 4; ++mf) {
                const int row = wr * 64 + mf * 16 + c;
                af[mf] = *(const short8*)(la + row * 128 +
                          ((kk * 64 + g * 16) ^ ((c & 7) << 4)));
            }
            #pragma unroll
            for (int nf = 0; nf < 2; ++nf) {
                const int row = wc * 32 + nf * 16 + c;
                bf[nf] = *(const short8*)(lb + row * 128 +
                          ((kk * 64 + g * 16) ^ ((c & 7) << 4)));
            }
            #pragma unroll
            for (int mf = 0; mf < 4; ++mf)
                #pragma unroll
                for (int nf = 0; nf < 2; ++nf)
                    acc[mf][nf] = __builtin_amdgcn_mfma_f32_16x16x32_bf16(
                        af[mf], bf[nf], acc[mf][nf], 0, 0, 0);
        }
        __syncthreads();
    }

    const int b      = m0 >> 11;
    const int s_base = m0 & 2047;
    #pragma unroll
    for (int nf = 0; nf < 2; ++nf) {
        const int ncol = n0 + wc * 32 + nf * 16 + c;
        const float bv = bias[ncol];
        const int h = ncol >> 6, dk = ncol & 63;
        #pragma unroll
        for (int mf = 0; mf < 4; ++mf) {
            if (OMODE == 1) {
                #pragma unroll
                for (int j = 0; j < 4; ++j) {
                    const int s = s_base + wr * 64 + mf * 16 + g * 4 + j;
                    out[(((size_t)(b * NHEADS + h) * S_LEN + s) * DK) + dk] =
                        f2bf((acc[mf][nf][j] + bv) * oscale);
                }
            } else {
                ushort4 v4;
                v4.x = f2bf((acc[mf][nf][0] + bv) * oscale);
                v4.y = f2bf((acc[mf][nf][1] + bv) * oscale);
                v4.z = f2bf((acc[mf][nf][2] + bv) * oscale);
                v4.w = f2bf((acc[mf][nf][3] + bv) * oscale);
                const int s = s_base + wr * 64 + mf * 16 + g * 4;
                *(ushort4*)&out[((size_t)(b * NHEADS + h) * DK + dk) * S_LEN + s] = v4;
            }
        }
    }
}

// ---------------------------------------------------------------------------
// Split (hi/lo) bf16 GEMM for O-projection: out fp32 = A @ Wt^T + bias.
// 3-term: Ahi*Whi + Ahi*Wlo + Alo*Whi. Single-buffered 48KB LDS.
// ---------------------------------------------------------------------------
__global__ __launch_bounds__(256)
void gemm_split_kernel(const ushort* __restrict__ Ahi, const ushort* __restrict__ Alo,
                       const ushort* __restrict__ Bhi, const ushort* __restrict__ Blo,
                       const float* __restrict__ bias, float* __restrict__ out)
{
    __shared__ __align__(16) ushort lds[24576];

    const int t = threadIdx.x, wv = t >> 6, lane = t & 63;
    const int c = lane & 15, g = lane >> 4;
    const int m0 = blockIdx.y * 128, n0 = blockIdx.x * 64;
    const int wr = wv >> 1, wc = wv & 1;
    const int lrow = lane >> 3, lcol = lane & 7;

    f32x4 acc[4][2];
    #pragma unroll
    for (int i = 0; i < 4; ++i)
        #pragma unroll
        for (int j = 0; j < 2; ++j)
            acc[i][j] = (f32x4){0.f, 0.f, 0.f, 0.f};

    for (int kt = 0; kt < 16; ++kt) {
        if (kt) __syncthreads();
        #pragma unroll
        for (int j = 0; j < 12; ++j) {
            const int ci = wv * 12 + j;
            ushort* dst = &lds[ci * 512];
            const ushort* src;
            int row, colb;
            if (ci < 16) {
                row = ci * 8 + lrow; colb = (lcol*16) ^ ((row&7)<<4);
                src = Ahi + (size_t)(m0+row)*1024 + kt*64 + (colb>>1);
            } else if (ci < 32) {
                row = (ci-16)*8 + lrow; colb = (lcol*16) ^ ((row&7)<<4);
                src = Alo + (size_t)(m0+row)*1024 + kt*64 + (colb>>1);
            } else if (ci < 40) {
                row = (ci-32)*8 + lrow; colb = (lcol*16) ^ ((row&7)<<4);
                src = Bhi + (size_t)(n0+row)*1024 + kt*64 + (colb>>1);
            } else {
                row = (ci-40)*8 + lrow; colb = (lcol*16) ^ ((row&7)<<4);
                src = Blo + (size_t)(n0+row)*1024 + kt*64 + (colb>>1);
            }
            gl_lds16(src, dst);
        }
        __syncthreads();

        const char* lah = (const char*)&lds[0];
        const char* lal = (const char*)&lds[8192];
        const char* lbh = (const char*)&lds[16384];
        const char* lbl = (const char*)&lds[20480];
        #pragma unroll
        for (int kk = 0; kk < 2; ++kk) {
            short8 ah[4], al[4], bh[2], bl[2];
            #pragma unroll
            for (int mf = 0; mf < 4; ++mf) {
                const int row = wr*64 + mf*16 + c;
                const int off = row*128 + ((kk*64 + g*16) ^ ((c&7)<<4));
                ah[mf] = *(const short8*)(lah + off);
                al[mf] = *(const short8*)(lal + off);
            }
            #pragma unroll
            for (int nf = 0; nf < 2; ++nf) {
                const int row = wc*32 + nf*16 + c;
                const int off = row*128 + ((kk*64 + g*16) ^ ((c&7)<<4));
                bh[nf] = *(const short8*)(lbh + off);
                bl[nf] = *(const short8*)(lbl + off);
            }
            #pragma unroll
            for (int mf = 0; mf < 4; ++mf)
                #pragma unroll
                for (int nf = 0; nf < 2; ++nf) {
                    acc[mf][nf] = __builtin_amdgcn_mfma_f32_16x16x32_bf16(ah[mf], bh[nf], acc[mf][nf], 0,0,0);
                    acc[mf][nf] = __builtin_amdgcn_mfma_f32_16x16x32_bf16(ah[mf], bl[nf], acc[mf][nf], 0,0,0);
                    acc[mf][nf] = __builtin_amdgcn_mfma_f32_16x16x32_bf16(al[mf], bh[nf], acc[mf][nf], 0,0,0);
                }
        }
    }

    #pragma unroll
    for (int nf = 0; nf < 2; ++nf) {
        const int ncol = n0 + wc*32 + nf*16 + c;
        const float bv = bias[ncol];
        #pragma unroll
        for (int mf = 0; mf < 4; ++mf)
            #pragma unroll
            for (int j = 0; j < 4; ++j) {
                const int m = m0 + wr*64 + mf*16 + g*4 + j;
                out[(size_t)m * 1024 + ncol] = acc[mf][nf][j] + bv;
            }
    }
}

// ---------------------------------------------------------------------------
// Flash attention, bf16 MFMA, 64-key LDS tiles (dbuf), defer-max softmax,
// cvt_pk P-packing, swizzled P buffer. LDS = 40960 B -> 4 blocks/CU.
// ---------------------------------------------------------------------------
__global__ __launch_bounds__(256, 4)
void attn_kernel3(const ushort* __restrict__ Qh, const ushort* __restrict__ Kh,
                  const ushort* __restrict__ Vt, ushort* __restrict__ ctx_hi,
                  ushort* __restrict__ ctx_lo)
{
    __shared__ __align__(16) ushort   KV[2][8192];     // 32 KB: K 8KB | V 8KB per buf
    __shared__ __align__(16) uint32_t Plds[4][512];    // 8 KB: per-wave P, swizzled

    const int t = threadIdx.x, wv = t >> 6, lane = t & 63;
    const int c = lane & 15, g = lane >> 4;
    const int bh = blockIdx.y;
    const int q0 = blockIdx.x * 64 + wv * 16;
    const int lrow = lane >> 3, lcol = lane & 7;

    const ushort* Kb = Kh + (size_t)bh * S_LEN * DK;
    const ushort* Vb = Vt + (size_t)bh * DK * S_LEN;

    const ushort* Qb = Qh + ((size_t)bh * S_LEN + q0 + c) * DK;
    short8 qf[2];
    qf[0] = *(const short8*)(Qb + g * 8);
    qf[1] = *(const short8*)(Qb + 32 + g * 8);

    auto stage = [&](int buf, int k0) {
        #pragma unroll
        for (int j = 0; j < 4; ++j) {
            const int ci = wv * 4 + j;
            ushort* dst = &KV[buf][ci * 512];
            const ushort* src;
            if (ci < 8) {
                const int row  = ci * 8 + lrow;
                const int colb = (lcol * 16) ^ ((row & 7) << 4);
                src = Kb + (size_t)(k0 + row) * DK + (colb >> 1);
            } else {
                const int row  = (ci - 8) * 8 + lrow;
                const int colb = (lcol * 16) ^ ((row & 7) << 4);
                src = Vb + (size_t)row * S_LEN + k0 + (colb >> 1);
            }
            gl_lds16(src, dst);
        }
    };

    float m = -3.0e38f, l = 0.f;
    f32x4 acc_o[4];
    #pragma unroll
    for (int i = 0; i < 4; ++i) acc_o[i] = (f32x4){0.f, 0.f, 0.f, 0.f};

    char* Pb = (char*)&Plds[wv][0];          // 2 KB per wave, rows=q (c), 128 B
    const int a7 = (c & 7) << 4;             // XOR swizzle (16B granule, bits 4-6)

    stage(0, 0);
    __syncthreads();

    for (int kt = 0; kt < 32; ++kt) {
        const int cur = kt & 1;
        if (kt < 31) stage(cur ^ 1, (kt + 1) * 64);

        const char* Kl = (const char*)&KV[cur][0];
        const char* Vl = (const char*)&KV[cur][4096];

        // ---- QK^T swapped: sa[kb][j] = S[key kb*16+g*4+j][q=c] ----
        f32x4 sa[4];
        #pragma unroll
        for (int kb = 0; kb < 4; ++kb) sa[kb] = (f32x4){0.f,0.f,0.f,0.f};
        #pragma unroll
        for (int kb = 0; kb < 4; ++kb) {
            const int row = kb * 16 + c;
            #pragma unroll
            for (int h = 0; h < 2; ++h) {
                short8 kf = *(const short8*)(Kl + row * 128 + ((h * 64 + g * 16) ^ a7));
                sa[kb] = __builtin_amdgcn_mfma_f32_16x16x32_bf16(kf, qf[h], sa[kb], 0,0,0);
            }
        }

        // ---- per-q max (replicated across g) ----
        float mt = sa[0][0];
        #pragma unroll
        for (int kb = 0; kb < 4; ++kb)
            #pragma unroll
            for (int j = 0; j < 4; ++j) mt = fmaxf(mt, sa[kb][j]);
        mt = fmaxf(mt, __shfl_xor(mt, 16));
        mt = fmaxf(mt, __shfl_xor(mt, 32));

        // ---- defer-max: rescale only when max grew past threshold ----
        if (__any(mt > m + 8.f)) {
            const float mnew = fmaxf(m, mt);
            const float corr = __builtin_amdgcn_exp2f(m - mnew);
            float corrj[4];
            #pragma unroll
            for (int j = 0; j < 4; ++j)
                corrj[j] = __shfl(corr, (lane & 48) | (g * 4 + j));
            #pragma unroll
            for (int db = 0; db < 4; ++db)
                #pragma unroll
                for (int j = 0; j < 4; ++j) acc_o[db][j] *= corrj[j];
            l *= corr;
            m = mnew;
        }

        // ---- P = exp2(s - m), row sum ----
        float p[16], ps = 0.f;
        #pragma unroll
        for (int kb = 0; kb < 4; ++kb)
            #pragma unroll
            for (int j = 0; j < 4; ++j) {
                float pp = __builtin_amdgcn_exp2f(sa[kb][j] - m);
                p[kb * 4 + j] = pp;
                ps += pp;
            }
        ps += __shfl_xor(ps, 16);
        ps += __shfl_xor(ps, 32);
        l += ps;

        // ---- P -> bf16 via cvt_pk, swizzled per-wave LDS roundtrip ----
        uint32_t u[8];
        #pragma unroll
        for (int i = 0; i < 8; ++i)
            asm("v_cvt_pk_bf16_f32 %0, %1, %2"
                : "=v"(u[i]) : "v"(p[2*i]), "v"(p[2*i+1]));
        #pragma unroll
        for (int kb = 0; kb < 4; ++kb) {
            uint2 w2; w2.x = u[2*kb]; w2.y = u[2*kb+1];
            *(uint2*)(Pb + c * 128 + ((kb * 32 + g * 8) ^ a7)) = w2;
        }
        short8 pa0 = *(const short8*)(Pb + c * 128 + ((g * 16) ^ a7));
        short8 pa1 = *(const short8*)(Pb + c * 128 + ((64 + g * 16) ^ a7));

        // ---- PV ----
        #pragma unroll
        for (int db = 0; db < 4; ++db) {
            const int row = db * 16 + c;
            short8 vf0 = *(const short8*)(Vl + row * 128 + ((g * 16) ^ a7));
            short8 vf1 = *(const short8*)(Vl + row * 128 + ((64 + g * 16) ^ a7));
            acc_o[db] = __builtin_amdgcn_mfma_f32_16x16x32_bf16(pa0, vf0, acc_o[db], 0,0,0);
            acc_o[db] = __builtin_amdgcn_mfma_f32_16x16x32_bf16(pa1, vf1, acc_o[db], 0,0,0);
        }
        __syncthreads();
    }

    // ---- epilogue ----
    float invj[4];
    #pragma unroll
    for (int j = 0; j < 4; ++j)
        invj[j] = 1.f / __shfl(l, (lane & 48) | (g * 4 + j));

    const int b = bh >> 4, h = bh & 15;
    #pragma unroll
    for (int db = 0; db < 4; ++db)
        #pragma unroll
        for (int j = 0; j < 4; ++j) {
            const float val = acc_o[db][j] * invj[j];
            const ushort hi = f2bf(val);
            const ushort lo = f2bf(val - bf2f(hi));
            const size_t idx = ((size_t)b * S_LEN + q0 + g * 4 + j) * DMODEL
                             + h * DK + db * 16 + c;
            ctx_hi[idx] = hi;
            ctx_lo[idx] = lo;
        }
}

// ---------------------------------------------------------------------------
extern "C" void kernel_launch(void* const* d_in, const int* in_sizes, int n_in,
                              void* d_out, int out_size, void* d_ws, size_t ws_size,
                              hipStream_t stream)
{
    const float* query  = (const float*)d_in[0];
    const float* key_in = (const float*)d_in[1];
    const float* value  = (const float*)d_in[2];
    const float* w_q = (const float*)d_in[3];
    const float* b_q = (const float*)d_in[4];
    const float* w_k = (const float*)d_in[5];
    const float* b_k = (const float*)d_in[6];
    const float* w_v = (const float*)d_in[7];
    const float* b_v = (const float*)d_in[8];
    const float* w_o = (const float*)d_in[9];
    const float* b_o = (const float*)d_in[10];
    float* out = (float*)d_out;

    const size_t E4M = (size_t)M_TOT * DMODEL;
    const size_t E1M = (size_t)DMODEL * DMODEL;

    ushort* ws = (ushort*)d_ws;
    ushort* Aq    = ws;
    ushort* Ak    = Aq + E4M;
    ushort* Av    = Ak + E4M;
    ushort* Qh    = Av + E4M;
    ushort* Kh    = Qh + E4M;
    ushort* Vt    = Kh + E4M;
    ushort* Wq    = Vt + E4M;
    ushort* Wk    = Wq + E1M;
    ushort* Wv    = Wk + E1M;
    ushort* Wo_hi = Wv + E1M;
    ushort* Wo_lo = Wo_hi + E1M;
    ushort* ctx_hi = Aq;
    ushort* ctx_lo = Ak;

    const float qscale = 0.125f * 1.44269504088896340736f;

    dim3 blk(256);
    hipLaunchKernelGGL(conv3_kernel, dim3(512, 1, 3), blk, 0, stream,
                       query, key_in, value, Aq, Ak, Av, (int)(E4M / 8));
    hipLaunchKernelGGL(wtrans3_kernel, dim3(16, 16, 3), blk, 0, stream,
                       w_q, w_k, w_v, Wq, Wk, Wv);
    hipLaunchKernelGGL(wtrans_o_kernel, dim3(16, 16), blk, 0, stream,
                       w_o, Wo_hi, Wo_lo);

    dim3 ggrd(DMODEL / 64, M_TOT / 128);
    hipLaunchKernelGGL((gemm_bf16_kernel<1>), ggrd, blk, 0, stream, Aq, Wq, b_q, Qh, qscale);
    hipLaunchKernelGGL((gemm_bf16_kernel<1>), ggrd, blk, 0, stream, Ak, Wk, b_k, Kh, 1.0f);
    hipLaunchKernelGGL((gemm_bf16_kernel<2>), ggrd, blk, 0, stream, Av, Wv, b_v, Vt, 1.0f);

    dim3 agrd(S_LEN / 64, BATCH * NHEADS);
    hipLaunchKernelGGL(attn_kernel3, agrd, blk, 0, stream, Qh, Kh, Vt, ctx_hi, ctx_lo);

    hipLaunchKernelGGL(gemm_split_kernel, ggrd, blk, 0, stream,
                       ctx_hi, ctx_lo, Wo_hi, Wo_lo, b_o, out);
}

// Round 5
// 149.397 us; speedup vs baseline: 10.7184x; 1.0714x over previous
//
#include <hip/hip_runtime.h>
#include <cstdint>

#define S_LEN 2048
#define DMODEL 1024
#define NHEADS 16
#define DK 64
#define BATCH 2
#define M_TOT 4096

typedef __attribute__((ext_vector_type(8)))  short  short8;   // 8 bf16 = 4 VGPRs
typedef __attribute__((ext_vector_type(4)))  float  f32x4;
typedef __attribute__((ext_vector_type(16))) float  f32x16;

__device__ __forceinline__ ushort f2bf(float f) {
    union { float f; uint32_t u; } v; v.f = f;
    uint32_t r = (v.u + 0x7fffu + ((v.u >> 16) & 1u)) >> 16;
    return (ushort)r;
}
__device__ __forceinline__ float bf2f(ushort u) {
    union { uint32_t u; float f; } v; v.u = ((uint32_t)u) << 16;
    return v.f;
}

__device__ __forceinline__ void gl_lds16(const void* g, void* l) {
    __builtin_amdgcn_global_load_lds(
        (const __attribute__((address_space(1))) void*)(g),
        (__attribute__((address_space(3))) void*)(l), 16, 0, 0);
}

// ---------------------------------------------------------------------------
// fused fp32 -> bf16 converter for q,k,v (blockIdx.z picks tensor)
// ---------------------------------------------------------------------------
__global__ __launch_bounds__(256)
void conv3_kernel(const float* __restrict__ a0, const float* __restrict__ a1,
                  const float* __restrict__ a2, ushort* __restrict__ o0,
                  ushort* __restrict__ o1, ushort* __restrict__ o2, int n8)
{
    const float*  in  = blockIdx.z == 0 ? a0 : (blockIdx.z == 1 ? a1 : a2);
    ushort*       out = blockIdx.z == 0 ? o0 : (blockIdx.z == 1 ? o1 : o2);
    int i = blockIdx.x * 256 + threadIdx.x;
    const int stride = gridDim.x * 256;
    for (; i < n8; i += stride) {
        const float4* p = (const float4*)(in + (size_t)i * 8);
        float4 a = p[0], b = p[1];
        ushort r[8];
        r[0]=f2bf(a.x); r[1]=f2bf(a.y); r[2]=f2bf(a.z); r[3]=f2bf(a.w);
        r[4]=f2bf(b.x); r[5]=f2bf(b.y); r[6]=f2bf(b.z); r[7]=f2bf(b.w);
        *(ushort4*)(out + (size_t)i * 8)     = *(ushort4*)&r[0];
        *(ushort4*)(out + (size_t)i * 8 + 4) = *(ushort4*)&r[4];
    }
}

// ---------------------------------------------------------------------------
// fused W[k][n] fp32 -> Wt[n][k] bf16 for w_q,w_k,w_v (blockIdx.z picks)
// ---------------------------------------------------------------------------
__global__ __launch_bounds__(256)
void wtrans3_kernel(const float* __restrict__ wq, const float* __restrict__ wk,
                    const float* __restrict__ wv, ushort* __restrict__ oq,
                    ushort* __restrict__ ok, ushort* __restrict__ ov)
{
    const float* w  = blockIdx.z == 0 ? wq : (blockIdx.z == 1 ? wk : wv);
    ushort*      hi = blockIdx.z == 0 ? oq : (blockIdx.z == 1 ? ok : ov);

    __shared__ float t[64][65];
    const int n0 = blockIdx.x * 64, k0 = blockIdx.y * 64;
    const int r  = threadIdx.x >> 2;
    const int cb = (threadIdx.x & 3) * 16;

    #pragma unroll
    for (int j = 0; j < 4; ++j) {
        float4 v = *(const float4*)(w + (size_t)(k0 + r) * DMODEL + n0 + cb + j * 4);
        t[r][cb + j*4 + 0] = v.x;
        t[r][cb + j*4 + 1] = v.y;
        t[r][cb + j*4 + 2] = v.z;
        t[r][cb + j*4 + 3] = v.w;
    }
    __syncthreads();

    ushort h8[16];
    #pragma unroll
    for (int j = 0; j < 16; ++j) h8[j] = f2bf(t[cb + j][r]);
    ushort* dsth = hi + (size_t)(n0 + r) * DMODEL + k0 + cb;
    *(ushort4*)(dsth + 0)  = *(ushort4*)&h8[0];
    *(ushort4*)(dsth + 4)  = *(ushort4*)&h8[4];
    *(ushort4*)(dsth + 8)  = *(ushort4*)&h8[8];
    *(ushort4*)(dsth + 12) = *(ushort4*)&h8[12];
}

// w_o: hi + lo split
__global__ __launch_bounds__(256)
void wtrans_o_kernel(const float* __restrict__ w, ushort* __restrict__ hi,
                     ushort* __restrict__ lo)
{
    __shared__ float t[64][65];
    const int n0 = blockIdx.x * 64, k0 = blockIdx.y * 64;
    const int r  = threadIdx.x >> 2;
    const int cb = (threadIdx.x & 3) * 16;

    #pragma unroll
    for (int j = 0; j < 4; ++j) {
        float4 v = *(const float4*)(w + (size_t)(k0 + r) * DMODEL + n0 + cb + j * 4);
        t[r][cb + j*4 + 0] = v.x;
        t[r][cb + j*4 + 1] = v.y;
        t[r][cb + j*4 + 2] = v.z;
        t[r][cb + j*4 + 3] = v.w;
    }
    __syncthreads();

    ushort h8[16], l8[16];
    #pragma unroll
    for (int j = 0; j < 16; ++j) {
        float x = t[cb + j][r];
        ushort h = f2bf(x);
        h8[j] = h;
        l8[j] = f2bf(x - bf2f(h));
    }
    ushort* dsth = hi + (size_t)(n0 + r) * DMODEL + k0 + cb;
    ushort* dstl = lo + (size_t)(n0 + r) * DMODEL + k0 + cb;
    #pragma unroll
    for (int j = 0; j < 4; ++j) {
        *(ushort4*)(dsth + j*4) = *(ushort4*)&h8[j*4];
        *(ushort4*)(dstl + j*4) = *(ushort4*)&l8[j*4];
    }
}

// ---------------------------------------------------------------------------
// bf16 MFMA GEMM:  C = A[M][1024] @ Wt[n][k]^T + bias
// BM=128 BN=64 BK=64, 256 thr = 4 waves (2x2), wave tile 64x32, dbuf LDS.
// OMODE 1: bf16 head-split [B,H,S,DK] * oscale;  OMODE 2: bf16 [B,H,DK,S].
// ---------------------------------------------------------------------------
template<int OMODE>
__global__ __launch_bounds__(256)
void gemm_bf16_kernel(const ushort* __restrict__ A, const ushort* __restrict__ Bt,
                      const float* __restrict__ bias, ushort* __restrict__ out,
                      float oscale)
{
    __shared__ __align__(16) ushort lds[2][12288];

    const int t = threadIdx.x, wv = t >> 6, lane = t & 63;
    const int c = lane & 15, g = lane >> 4;
    const int m0 = blockIdx.y * 128, n0 = blockIdx.x * 64;
    const int wr = wv >> 1, wc = wv & 1;
    const int lrow = lane >> 3, lcol = lane & 7;

    f32x4 acc[4][2];
    #pragma unroll
    for (int i = 0; i < 4; ++i)
        #pragma unroll
        for (int j = 0; j < 2; ++j)
            acc[i][j] = (f32x4){0.f, 0.f, 0.f, 0.f};

    auto stage = [&](int buf, int kt) {
        #pragma unroll
        for (int j = 0; j < 6; ++j) {
            const int ci = wv * 6 + j;
            ushort* dst = &lds[buf][ci * 512];
            const ushort* src;
            if (ci < 16) {
                const int row  = ci * 8 + lrow;
                const int colb = (lcol * 16) ^ ((row & 7) << 4);
                src = A + (size_t)(m0 + row) * 1024 + kt * 64 + (colb >> 1);
            } else {
                const int row  = (ci - 16) * 8 + lrow;
                const int colb = (lcol * 16) ^ ((row & 7) << 4);
                src = Bt + (size_t)(n0 + row) * 1024 + kt * 64 + (colb >> 1);
            }
            gl_lds16(src, dst);
        }
    };

    stage(0, 0);
    __syncthreads();

    for (int kt = 0; kt < 16; ++kt) {
        const int cur = kt & 1;
        if (kt < 15) stage(cur ^ 1, kt + 1);

        const char* la = (const char*)&lds[cur][0];
        const char* lb = (const char*)&lds[cur][8192];
        #pragma unroll
        for (int kk = 0; kk < 2; ++kk) {
            short8 af[4], bf[2];
            #pragma unroll
            for (int mf = 0; mf < 4; ++mf) {
                const int row = wr * 64 + mf * 16 + c;
                af[mf] = *(const short8*)(la + row * 128 +
                          ((kk * 64 + g * 16) ^ ((c & 7) << 4)));
            }
            #pragma unroll
            for (int nf = 0; nf < 2; ++nf) {
                const int row = wc * 32 + nf * 16 + c;
                bf[nf] = *(const short8*)(lb + row * 128 +
                          ((kk * 64 + g * 16) ^ ((c & 7) << 4)));
            }
            #pragma unroll
            for (int mf = 0; mf < 4; ++mf)
                #pragma unroll
                for (int nf = 0; nf < 2; ++nf)
                    acc[mf][nf] = __builtin_amdgcn_mfma_f32_16x16x32_bf16(
                        af[mf], bf[nf], acc[mf][nf], 0, 0, 0);
        }
        __syncthreads();
    }

    const int b      = m0 >> 11;
    const int s_base = m0 & 2047;
    #pragma unroll
    for (int nf = 0; nf < 2; ++nf) {
        const int ncol = n0 + wc * 32 + nf * 16 + c;
        const float bv = bias[ncol];
        const int h = ncol >> 6, dk = ncol & 63;
        #pragma unroll
        for (int mf = 0; mf < 4; ++mf) {
            if (OMODE == 1) {
                #pragma unroll
                for (int j = 0; j < 4; ++j) {
                    const int s = s_base + wr * 64 + mf * 16 + g * 4 + j;
                    out[(((size_t)(b * NHEADS + h) * S_LEN + s) * DK) + dk] =
                        f2bf((acc[mf][nf][j] + bv) * oscale);
                }
            } else {
                ushort4 v4;
                v4.x = f2bf((acc[mf][nf][0] + bv) * oscale);
                v4.y = f2bf((acc[mf][nf][1] + bv) * oscale);
                v4.z = f2bf((acc[mf][nf][2] + bv) * oscale);
                v4.w = f2bf((acc[mf][nf][3] + bv) * oscale);
                const int s = s_base + wr * 64 + mf * 16 + g * 4;
                *(ushort4*)&out[((size_t)(b * NHEADS + h) * DK + dk) * S_LEN + s] = v4;
            }
        }
    }
}

// ---------------------------------------------------------------------------
// Split (hi/lo) bf16 GEMM for O-projection: out fp32 = A @ Wt^T + bias.
// ---------------------------------------------------------------------------
__global__ __launch_bounds__(256)
void gemm_split_kernel(const ushort* __restrict__ Ahi, const ushort* __restrict__ Alo,
                       const ushort* __restrict__ Bhi, const ushort* __restrict__ Blo,
                       const float* __restrict__ bias, float* __restrict__ out)
{
    __shared__ __align__(16) ushort lds[24576];

    const int t = threadIdx.x, wv = t >> 6, lane = t & 63;
    const int c = lane & 15, g = lane >> 4;
    const int m0 = blockIdx.y * 128, n0 = blockIdx.x * 64;
    const int wr = wv >> 1, wc = wv & 1;
    const int lrow = lane >> 3, lcol = lane & 7;

    f32x4 acc[4][2];
    #pragma unroll
    for (int i = 0; i < 4; ++i)
        #pragma unroll
        for (int j = 0; j < 2; ++j)
            acc[i][j] = (f32x4){0.f, 0.f, 0.f, 0.f};

    for (int kt = 0; kt < 16; ++kt) {
        if (kt) __syncthreads();
        #pragma unroll
        for (int j = 0; j < 12; ++j) {
            const int ci = wv * 12 + j;
            ushort* dst = &lds[ci * 512];
            const ushort* src;
            int row, colb;
            if (ci < 16) {
                row = ci * 8 + lrow; colb = (lcol*16) ^ ((row&7)<<4);
                src = Ahi + (size_t)(m0+row)*1024 + kt*64 + (colb>>1);
            } else if (ci < 32) {
                row = (ci-16)*8 + lrow; colb = (lcol*16) ^ ((row&7)<<4);
                src = Alo + (size_t)(m0+row)*1024 + kt*64 + (colb>>1);
            } else if (ci < 40) {
                row = (ci-32)*8 + lrow; colb = (lcol*16) ^ ((row&7)<<4);
                src = Bhi + (size_t)(n0+row)*1024 + kt*64 + (colb>>1);
            } else {
                row = (ci-40)*8 + lrow; colb = (lcol*16) ^ ((row&7)<<4);
                src = Blo + (size_t)(n0+row)*1024 + kt*64 + (colb>>1);
            }
            gl_lds16(src, dst);
        }
        __syncthreads();

        const char* lah = (const char*)&lds[0];
        const char* lal = (const char*)&lds[8192];
        const char* lbh = (const char*)&lds[16384];
        const char* lbl = (const char*)&lds[20480];
        #pragma unroll
        for (int kk = 0; kk < 2; ++kk) {
            short8 ah[4], al[4], bh[2], bl[2];
            #pragma unroll
            for (int mf = 0; mf < 4; ++mf) {
                const int row = wr*64 + mf*16 + c;
                const int off = row*128 + ((kk*64 + g*16) ^ ((c&7)<<4));
                ah[mf] = *(const short8*)(lah + off);
                al[mf] = *(const short8*)(lal + off);
            }
            #pragma unroll
            for (int nf = 0; nf < 2; ++nf) {
                const int row = wc*32 + nf*16 + c;
                const int off = row*128 + ((kk*64 + g*16) ^ ((c&7)<<4));
                bh[nf] = *(const short8*)(lbh + off);
                bl[nf] = *(const short8*)(lbl + off);
            }
            #pragma unroll
            for (int mf = 0; mf < 4; ++mf)
                #pragma unroll
                for (int nf = 0; nf < 2; ++nf) {
                    acc[mf][nf] = __builtin_amdgcn_mfma_f32_16x16x32_bf16(ah[mf], bh[nf], acc[mf][nf], 0,0,0);
                    acc[mf][nf] = __builtin_amdgcn_mfma_f32_16x16x32_bf16(ah[mf], bl[nf], acc[mf][nf], 0,0,0);
                    acc[mf][nf] = __builtin_amdgcn_mfma_f32_16x16x32_bf16(al[mf], bh[nf], acc[mf][nf], 0,0,0);
                }
        }
    }

    #pragma unroll
    for (int nf = 0; nf < 2; ++nf) {
        const int ncol = n0 + wc*32 + nf*16 + c;
        const float bv = bias[ncol];
        #pragma unroll
        for (int mf = 0; mf < 4; ++mf)
            #pragma unroll
            for (int j = 0; j < 4; ++j) {
                const int m = m0 + wr*64 + mf*16 + g*4 + j;
                out[(size_t)m * 1024 + ncol] = acc[mf][nf][j] + bv;
            }
    }
}

// ---------------------------------------------------------------------------
// Flash attention, 32x32x16 MFMA, lane-local softmax, in-register P via
// cvt_pk + permlane32_swap (no P LDS). 4 waves x 32 q rows = 128 q / block.
// KV tile 64 keys, dbuf, global_load_lds with pre-swizzled sources.
// K LDS: [64 key][128B, XOR-swz]; V LDS: 2 groups of [32 r][128B] where
// row r holds d=r (left 64B) and d=r+32 (right), XOR-swz, group=32 keys.
// ---------------------------------------------------------------------------
__global__ __launch_bounds__(256, 2)
void attn_kernel4(const ushort* __restrict__ Qh, const ushort* __restrict__ Kh,
                  const ushort* __restrict__ Vt, ushort* __restrict__ ctx_hi,
                  ushort* __restrict__ ctx_lo)
{
    __shared__ __align__(16) ushort KV[2][8192];   // 2 x 16KB (K 8KB | V 8KB)

    const int t  = threadIdx.x, wv = t >> 6, lane = t & 63;
    const int q  = lane & 31;          // q column owned by this lane
    const int hi = lane >> 5;          // 0/1
    const int bh = blockIdx.y;
    const int q0 = blockIdx.x * 128 + wv * 32;

    const ushort* Kb = Kh + (size_t)bh * S_LEN * DK;
    const ushort* Vb = Vt + (size_t)bh * DK * S_LEN;
    const ushort* Qb = Qh + ((size_t)bh * S_LEN + q0 + q) * DK;

    // Q B-fragments: slice s -> k = s*16 + hi*8 + i (contiguous 16B)
    short8 qf[4];
    #pragma unroll
    for (int s = 0; s < 4; ++s)
        qf[s] = *(const short8*)(Qb + s * 16 + hi * 8);

    // ---- precompute staging src/dst (k0-invariant parts) ----
    const ushort* sbase[4];
    int sstr[4];
    char* dbase[4];
    #pragma unroll
    for (int j = 0; j < 4; ++j) {
        const int D = (j * 256 + t) * 16;      // dest byte in 16KB tile
        dbase[j] = (char*)&KV[0][0] + D;
        if (D < 8192) {                        // K: row=key, 128B rows
            const int row = D >> 7;
            const int X   = D & 127;
            const int Xs  = X ^ ((row & 7) << 4);
            sbase[j] = Kb + row * DK + (Xs >> 1);
            sstr[j]  = DK;                     // advance k0 keys
        } else {                               // V: group kk, row r
            const int Y   = D - 8192;
            const int kk  = Y >> 12;
            const int Z   = Y & 4095;
            const int r   = Z >> 7;
            const int gsl = ((Z & 127) >> 4) ^ (r & 7);
            const int d   = r + ((gsl >> 2) << 5);
            sbase[j] = Vb + (size_t)d * S_LEN + kk * 32 + (gsl & 3) * 8;
            sstr[j]  = 1;                      // advance k0 elements
        }
    }
    auto stage = [&](int buf, int k0) {
        #pragma unroll
        for (int j = 0; j < 4; ++j)
            gl_lds16(sbase[j] + (size_t)k0 * sstr[j], dbase[j] + buf * 16384);
    };

    float m = -3.0e38f, l = 0.f;
    f32x16 accO[2];
    #pragma unroll
    for (int i = 0; i < 16; ++i) { accO[0][i] = 0.f; accO[1][i] = 0.f; }

    const int swz = (q & 7) << 4;

    stage(0, 0);
    __syncthreads();

    for (int kt = 0; kt < 32; ++kt) {
        const int cur = kt & 1;
        if (kt < 31) stage(cur ^ 1, (kt + 1) * 64);

        const char* Kl = (const char*)&KV[cur][0];
        const char* Vl = Kl + 8192;

        #pragma unroll
        for (int kk = 0; kk < 2; ++kk) {
            // ---- S^T = K (A) x Q^T (B): 32 keys x 32 q, K=64 in 4 slices
            f32x16 sa;
            #pragma unroll
            for (int i = 0; i < 16; ++i) sa[i] = 0.f;
            #pragma unroll
            for (int s = 0; s < 4; ++s) {
                short8 kf = *(const short8*)(Kl + (kk * 32 + q) * 128 +
                                             ((s * 32 + hi * 16) ^ swz));
                sa = __builtin_amdgcn_mfma_f32_32x32x16_bf16(kf, qf[s], sa, 0, 0, 0);
            }
            // lane holds 16 scores, all for q-col q: key = kk*32 + (r&3)+8*(r>>2)+4*hi

            // ---- lane-local max + pair-exchange ----
            float mt = sa[0];
            #pragma unroll
            for (int r = 1; r < 16; ++r) mt = fmaxf(mt, sa[r]);
            mt = fmaxf(mt, __shfl_xor(mt, 32));

            // ---- defer-max rescale (lane-local corr!) ----
            if (__any(mt > m + 8.f)) {
                const float mnew = fmaxf(m, mt);
                const float corr = __builtin_amdgcn_exp2f(m - mnew);
                #pragma unroll
                for (int r = 0; r < 16; ++r) { accO[0][r] *= corr; accO[1][r] *= corr; }
                l *= corr;
                m = mnew;
            }

            // ---- P = exp2(s-m), lane-local sum ----
            float p[16], ps = 0.f;
            #pragma unroll
            for (int r = 0; r < 16; ++r) {
                p[r] = __builtin_amdgcn_exp2f(sa[r] - m);
                ps += p[r];
            }
            ps += __shfl_xor(ps, 32);
            l += ps;

            // ---- pack to bf16 pairs; permlane32_swap -> PV B-fragments ----
            uint32_t u[8];
            #pragma unroll
            for (int jj = 0; jj < 8; ++jj)
                asm("v_cvt_pk_bf16_f32 %0, %1, %2"
                    : "=v"(u[jj]) : "v"(p[2*jj]), "v"(p[2*jj+1]));
            asm("v_permlane32_swap_b32 %0, %1" : "+v"(u[0]), "+v"(u[2]));
            asm("v_permlane32_swap_b32 %0, %1" : "+v"(u[1]), "+v"(u[3]));
            asm("v_permlane32_swap_b32 %0, %1" : "+v"(u[4]), "+v"(u[6]));
            asm("v_permlane32_swap_b32 %0, %1" : "+v"(u[5]), "+v"(u[7]));
            union { uint32_t w[4]; short8 s8; } pb0, pb1;
            pb0.w[0]=u[0]; pb0.w[1]=u[1]; pb0.w[2]=u[2]; pb0.w[3]=u[3];
            pb1.w[0]=u[4]; pb1.w[1]=u[5]; pb1.w[2]=u[6]; pb1.w[3]=u[7];

            // ---- PV: O^T[d][q] += V^T (A) x P (B), d-blocks x key-slices ----
            const char* Vg = Vl + kk * 4096;
            #pragma unroll
            for (int db = 0; db < 2; ++db) {
                short8 vf0 = *(const short8*)(Vg + q * 128 + ((db*64 +      hi*16) ^ swz));
                short8 vf1 = *(const short8*)(Vg + q * 128 + ((db*64 + 32 + hi*16) ^ swz));
                accO[db] = __builtin_amdgcn_mfma_f32_32x32x16_bf16(vf0, pb0.s8, accO[db], 0, 0, 0);
                accO[db] = __builtin_amdgcn_mfma_f32_32x32x16_bf16(vf1, pb1.s8, accO[db], 0, 0, 0);
            }
        }
        __syncthreads();
    }

    // ---- epilogue: /l, scatter bf16 hi/lo ----
    const float inv = 1.f / l;
    const int b = bh >> 4, h = bh & 15;
    ushort* base_hi = ctx_hi + ((size_t)b * S_LEN + q0 + q) * DMODEL + h * DK;
    ushort* base_lo = ctx_lo + ((size_t)b * S_LEN + q0 + q) * DMODEL + h * DK;
    #pragma unroll
    for (int db = 0; db < 2; ++db)
        #pragma unroll
        for (int r = 0; r < 16; ++r) {
            const int d = db * 32 + (r & 3) + 8 * (r >> 2) + 4 * hi;
            const float val = accO[db][r] * inv;
            const ushort vh = f2bf(val);
            base_hi[d] = vh;
            base_lo[d] = f2bf(val - bf2f(vh));
        }
}

// ---------------------------------------------------------------------------
extern "C" void kernel_launch(void* const* d_in, const int* in_sizes, int n_in,
                              void* d_out, int out_size, void* d_ws, size_t ws_size,
                              hipStream_t stream)
{
    const float* query  = (const float*)d_in[0];
    const float* key_in = (const float*)d_in[1];
    const float* value  = (const float*)d_in[2];
    const float* w_q = (const float*)d_in[3];
    const float* b_q = (const float*)d_in[4];
    const float* w_k = (const float*)d_in[5];
    const float* b_k = (const float*)d_in[6];
    const float* w_v = (const float*)d_in[7];
    const float* b_v = (const float*)d_in[8];
    const float* w_o = (const float*)d_in[9];
    const float* b_o = (const float*)d_in[10];
    float* out = (float*)d_out;

    const size_t E4M = (size_t)M_TOT * DMODEL;
    const size_t E1M = (size_t)DMODEL * DMODEL;

    ushort* ws = (ushort*)d_ws;
    ushort* Aq    = ws;
    ushort* Ak    = Aq + E4M;
    ushort* Av    = Ak + E4M;
    ushort* Qh    = Av + E4M;
    ushort* Kh    = Qh + E4M;
    ushort* Vt    = Kh + E4M;
    ushort* Wq    = Vt + E4M;
    ushort* Wk    = Wq + E1M;
    ushort* Wv    = Wk + E1M;
    ushort* Wo_hi = Wv + E1M;
    ushort* Wo_lo = Wo_hi + E1M;
    ushort* ctx_hi = Aq;
    ushort* ctx_lo = Ak;

    const float qscale = 0.125f * 1.44269504088896340736f;

    dim3 blk(256);
    hipLaunchKernelGGL(conv3_kernel, dim3(512, 1, 3), blk, 0, stream,
                       query, key_in, value, Aq, Ak, Av, (int)(E4M / 8));
    hipLaunchKernelGGL(wtrans3_kernel, dim3(16, 16, 3), blk, 0, stream,
                       w_q, w_k, w_v, Wq, Wk, Wv);
    hipLaunchKernelGGL(wtrans_o_kernel, dim3(16, 16), blk, 0, stream,
                       w_o, Wo_hi, Wo_lo);

    dim3 ggrd(DMODEL / 64, M_TOT / 128);
    hipLaunchKernelGGL((gemm_bf16_kernel<1>), ggrd, blk, 0, stream, Aq, Wq, b_q, Qh, qscale);
    hipLaunchKernelGGL((gemm_bf16_kernel<1>), ggrd, blk, 0, stream, Ak, Wk, b_k, Kh, 1.0f);
    hipLaunchKernelGGL((gemm_bf16_kernel<2>), ggrd, blk, 0, stream, Av, Wv, b_v, Vt, 1.0f);

    dim3 agrd(S_LEN / 128, BATCH * NHEADS);
    hipLaunchKernelGGL(attn_kernel4, agrd, blk, 0, stream, Qh, Kh, Vt, ctx_hi, ctx_lo);

    hipLaunchKernelGGL(gemm_split_kernel, ggrd, blk, 0, stream,
                       ctx_hi, ctx_lo, Wo_hi, Wo_lo, b_o, out);
}

// Round 6
// 130.305 us; speedup vs baseline: 12.2888x; 1.1465x over previous
//
#include <hip/hip_runtime.h>
#include <cstdint>

#define S_LEN 2048
#define DMODEL 1024
#define NHEADS 16
#define DK 64
#define BATCH 2
#define M_TOT 4096

typedef __attribute__((ext_vector_type(8)))  short  short8;   // 8 bf16 = 4 VGPRs
typedef __attribute__((ext_vector_type(4)))  float  f32x4;
typedef __attribute__((ext_vector_type(16))) float  f32x16;

__device__ __forceinline__ ushort f2bf(float f) {
    union { float f; uint32_t u; } v; v.f = f;
    uint32_t r = (v.u + 0x7fffu + ((v.u >> 16) & 1u)) >> 16;
    return (ushort)r;
}
__device__ __forceinline__ float bf2f(ushort u) {
    union { uint32_t u; float f; } v; v.u = ((uint32_t)u) << 16;
    return v.f;
}
__device__ __forceinline__ float max3f(float a, float b, float c) {
    float d;
    asm("v_max3_f32 %0, %1, %2, %3" : "=v"(d) : "v"(a), "v"(b), "v"(c));
    return d;
}

__device__ __forceinline__ void gl_lds16(const void* g, void* l) {
    __builtin_amdgcn_global_load_lds(
        (const __attribute__((address_space(1))) void*)(g),
        (__attribute__((address_space(3))) void*)(l), 16, 0, 0);
}

// ---------------------------------------------------------------------------
// fused fp32 -> bf16 converter for q,k,v (blockIdx.z picks tensor)
// ---------------------------------------------------------------------------
__global__ __launch_bounds__(256)
void conv3_kernel(const float* __restrict__ a0, const float* __restrict__ a1,
                  const float* __restrict__ a2, ushort* __restrict__ o0,
                  ushort* __restrict__ o1, ushort* __restrict__ o2, int n8)
{
    const float*  in  = blockIdx.z == 0 ? a0 : (blockIdx.z == 1 ? a1 : a2);
    ushort*       out = blockIdx.z == 0 ? o0 : (blockIdx.z == 1 ? o1 : o2);
    int i = blockIdx.x * 256 + threadIdx.x;
    const int stride = gridDim.x * 256;
    for (; i < n8; i += stride) {
        const float4* p = (const float4*)(in + (size_t)i * 8);
        float4 a = p[0], b = p[1];
        ushort r[8];
        r[0]=f2bf(a.x); r[1]=f2bf(a.y); r[2]=f2bf(a.z); r[3]=f2bf(a.w);
        r[4]=f2bf(b.x); r[5]=f2bf(b.y); r[6]=f2bf(b.z); r[7]=f2bf(b.w);
        *(ushort4*)(out + (size_t)i * 8)     = *(ushort4*)&r[0];
        *(ushort4*)(out + (size_t)i * 8 + 4) = *(ushort4*)&r[4];
    }
}

// ---------------------------------------------------------------------------
// fused W[k][n] fp32 -> Wt[n][k] bf16. z=0..2: w_q/w_k/w_v (hi only);
// z=3: w_o (hi + lo split).
// ---------------------------------------------------------------------------
__global__ __launch_bounds__(256)
void wtrans4_kernel(const float* __restrict__ wq, const float* __restrict__ wk,
                    const float* __restrict__ wv, const float* __restrict__ wo,
                    ushort* __restrict__ oq, ushort* __restrict__ ok,
                    ushort* __restrict__ ov, ushort* __restrict__ oo_hi,
                    ushort* __restrict__ oo_lo)
{
    const int z = blockIdx.z;
    const float* w  = z == 0 ? wq : (z == 1 ? wk : (z == 2 ? wv : wo));
    ushort*      hi = z == 0 ? oq : (z == 1 ? ok : (z == 2 ? ov : oo_hi));
    const bool   LO = (z == 3);

    __shared__ float t[64][65];
    const int n0 = blockIdx.x * 64, k0 = blockIdx.y * 64;
    const int r  = threadIdx.x >> 2;
    const int cb = (threadIdx.x & 3) * 16;

    #pragma unroll
    for (int j = 0; j < 4; ++j) {
        float4 v = *(const float4*)(w + (size_t)(k0 + r) * DMODEL + n0 + cb + j * 4);
        t[r][cb + j*4 + 0] = v.x;
        t[r][cb + j*4 + 1] = v.y;
        t[r][cb + j*4 + 2] = v.z;
        t[r][cb + j*4 + 3] = v.w;
    }
    __syncthreads();

    ushort h8[16], l8[16];
    #pragma unroll
    for (int j = 0; j < 16; ++j) {
        float x = t[cb + j][r];
        ushort h = f2bf(x);
        h8[j] = h;
        l8[j] = f2bf(x - bf2f(h));
    }
    ushort* dsth = hi + (size_t)(n0 + r) * DMODEL + k0 + cb;
    #pragma unroll
    for (int j = 0; j < 4; ++j)
        *(ushort4*)(dsth + j*4) = *(ushort4*)&h8[j*4];
    if (LO) {
        ushort* dstl = oo_lo + (size_t)(n0 + r) * DMODEL + k0 + cb;
        #pragma unroll
        for (int j = 0; j < 4; ++j)
            *(ushort4*)(dstl + j*4) = *(ushort4*)&l8[j*4];
    }
}

// ---------------------------------------------------------------------------
// Fused QKV bf16 MFMA GEMM. blockIdx.z picks projection.
// C = A[M][1024] @ Wt[n][k]^T + bias.  BM=128 BN=64 BK=64, 4 waves, dbuf.
// z=0: Qh [B,H,S,DK]*qscale; z=1: Kh [B,H,S,DK]; z=2: Vt [B,H,DK,S].
// ---------------------------------------------------------------------------
__global__ __launch_bounds__(256)
void gemm_qkv_kernel(const ushort* __restrict__ Aq, const ushort* __restrict__ Ak,
                     const ushort* __restrict__ Av, const ushort* __restrict__ Wq,
                     const ushort* __restrict__ Wk, const ushort* __restrict__ Wv,
                     const float* __restrict__ bq, const float* __restrict__ bk,
                     const float* __restrict__ bv, ushort* __restrict__ Qh,
                     ushort* __restrict__ Kh, ushort* __restrict__ Vt, float qscale)
{
    const int z = blockIdx.z;
    const ushort* A    = z == 0 ? Aq : (z == 1 ? Ak : Av);
    const ushort* Bt   = z == 0 ? Wq : (z == 1 ? Wk : Wv);
    const float*  bias = z == 0 ? bq : (z == 1 ? bk : bv);
    ushort*       out  = z == 0 ? Qh : (z == 1 ? Kh : Vt);
    const float oscale = z == 0 ? qscale : 1.0f;
    const int   mode   = z == 2 ? 2 : 1;

    __shared__ __align__(16) ushort lds[2][12288];

    const int t = threadIdx.x, wv = t >> 6, lane = t & 63;
    const int c = lane & 15, g = lane >> 4;
    const int m0 = blockIdx.y * 128, n0 = blockIdx.x * 64;
    const int wr = wv >> 1, wc = wv & 1;
    const int lrow = lane >> 3, lcol = lane & 7;

    f32x4 acc[4][2];
    #pragma unroll
    for (int i = 0; i < 4; ++i)
        #pragma unroll
        for (int j = 0; j < 2; ++j)
            acc[i][j] = (f32x4){0.f, 0.f, 0.f, 0.f};

    auto stage = [&](int buf, int kt) {
        #pragma unroll
        for (int j = 0; j < 6; ++j) {
            const int ci = wv * 6 + j;
            ushort* dst = &lds[buf][ci * 512];
            const ushort* src;
            if (ci < 16) {
                const int row  = ci * 8 + lrow;
                const int colb = (lcol * 16) ^ ((row & 7) << 4);
                src = A + (size_t)(m0 + row) * 1024 + kt * 64 + (colb >> 1);
            } else {
                const int row  = (ci - 16) * 8 + lrow;
                const int colb = (lcol * 16) ^ ((row & 7) << 4);
                src = Bt + (size_t)(n0 + row) * 1024 + kt * 64 + (colb >> 1);
            }
            gl_lds16(src, dst);
        }
    };

    stage(0, 0);
    __syncthreads();

    for (int kt = 0; kt < 16; ++kt) {
        const int cur = kt & 1;
        if (kt < 15) stage(cur ^ 1, kt + 1);

        const char* la = (const char*)&lds[cur][0];
        const char* lb = (const char*)&lds[cur][8192];
        #pragma unroll
        for (int kk = 0; kk < 2; ++kk) {
            short8 af[4], bf[2];
            #pragma unroll
            for (int mf = 0; mf < 4; ++mf) {
                const int row = wr * 64 + mf * 16 + c;
                af[mf] = *(const short8*)(la + row * 128 +
                          ((kk * 64 + g * 16) ^ ((c & 7) << 4)));
            }
            #pragma unroll
            for (int nf = 0; nf < 2; ++nf) {
                const int row = wc * 32 + nf * 16 + c;
                bf[nf] = *(const short8*)(lb + row * 128 +
                          ((kk * 64 + g * 16) ^ ((c & 7) << 4)));
            }
            #pragma unroll
            for (int mf = 0; mf < 4; ++mf)
                #pragma unroll
                for (int nf = 0; nf < 2; ++nf)
                    acc[mf][nf] = __builtin_amdgcn_mfma_f32_16x16x32_bf16(
                        af[mf], bf[nf], acc[mf][nf], 0, 0, 0);
        }
        __syncthreads();
    }

    const int b      = m0 >> 11;
    const int s_base = m0 & 2047;
    #pragma unroll
    for (int nf = 0; nf < 2; ++nf) {
        const int ncol = n0 + wc * 32 + nf * 16 + c;
        const float bv = bias[ncol];
        const int h = ncol >> 6, dk = ncol & 63;
        #pragma unroll
        for (int mf = 0; mf < 4; ++mf) {
            if (mode == 1) {
                #pragma unroll
                for (int j = 0; j < 4; ++j) {
                    const int s = s_base + wr * 64 + mf * 16 + g * 4 + j;
                    out[(((size_t)(b * NHEADS + h) * S_LEN + s) * DK) + dk] =
                        f2bf((acc[mf][nf][j] + bv) * oscale);
                }
            } else {
                ushort4 v4;
                v4.x = f2bf(acc[mf][nf][0] + bv);
                v4.y = f2bf(acc[mf][nf][1] + bv);
                v4.z = f2bf(acc[mf][nf][2] + bv);
                v4.w = f2bf(acc[mf][nf][3] + bv);
                const int s = s_base + wr * 64 + mf * 16 + g * 4;
                *(ushort4*)&out[((size_t)(b * NHEADS + h) * DK + dk) * S_LEN + s] = v4;
            }
        }
    }
}

// ---------------------------------------------------------------------------
// O-projection GEMM, 2-term W-split: out fp32 = A @ (Whi + Wlo)^T + bias.
// A = ctx bf16. BM=128 BN=64 BK=64, 4 waves, dbuf 64KB LDS.
// Per K-tile: 16 ds_read_b128, 32 MFMA.
// ---------------------------------------------------------------------------
__global__ __launch_bounds__(256)
void gemm_o2_kernel(const ushort* __restrict__ A, const ushort* __restrict__ Bhi,
                    const ushort* __restrict__ Blo, const float* __restrict__ bias,
                    float* __restrict__ out)
{
    __shared__ __align__(16) ushort lds[2][16384];   // A 16KB | Bhi 8KB | Blo 8KB

    const int t = threadIdx.x, wv = t >> 6, lane = t & 63;
    const int c = lane & 15, g = lane >> 4;
    const int m0 = blockIdx.y * 128, n0 = blockIdx.x * 64;
    const int wr = wv >> 1, wc = wv & 1;
    const int lrow = lane >> 3, lcol = lane & 7;

    f32x4 acc[4][2];
    #pragma unroll
    for (int i = 0; i < 4; ++i)
        #pragma unroll
        for (int j = 0; j < 2; ++j)
            acc[i][j] = (f32x4){0.f, 0.f, 0.f, 0.f};

    auto stage = [&](int buf, int kt) {
        #pragma unroll
        for (int j = 0; j < 8; ++j) {
            const int ci = wv * 8 + j;
            ushort* dst = &lds[buf][ci * 512];
            const ushort* src;
            if (ci < 16) {
                const int row  = ci * 8 + lrow;
                const int colb = (lcol * 16) ^ ((row & 7) << 4);
                src = A + (size_t)(m0 + row) * 1024 + kt * 64 + (colb >> 1);
            } else if (ci < 24) {
                const int row  = (ci - 16) * 8 + lrow;
                const int colb = (lcol * 16) ^ ((row & 7) << 4);
                src = Bhi + (size_t)(n0 + row) * 1024 + kt * 64 + (colb >> 1);
            } else {
                const int row  = (ci - 24) * 8 + lrow;
                const int colb = (lcol * 16) ^ ((row & 7) << 4);
                src = Blo + (size_t)(n0 + row) * 1024 + kt * 64 + (colb >> 1);
            }
            gl_lds16(src, dst);
        }
    };

    stage(0, 0);
    __syncthreads();

    for (int kt = 0; kt < 16; ++kt) {
        const int cur = kt & 1;
        if (kt < 15) stage(cur ^ 1, kt + 1);

        const char* la = (const char*)&lds[cur][0];
        const char* lh = (const char*)&lds[cur][8192];
        const char* ll = (const char*)&lds[cur][12288];
        #pragma unroll
        for (int kk = 0; kk < 2; ++kk) {
            short8 af[4], bh[2], bl[2];
            #pragma unroll
            for (int mf = 0; mf < 4; ++mf) {
                const int row = wr * 64 + mf * 16 + c;
                af[mf] = *(const short8*)(la + row * 128 +
                          ((kk * 64 + g * 16) ^ ((c & 7) << 4)));
            }
            #pragma unroll
            for (int nf = 0; nf < 2; ++nf) {
                const int row = wc * 32 + nf * 16 + c;
                const int off = row * 128 + ((kk * 64 + g * 16) ^ ((c & 7) << 4));
                bh[nf] = *(const short8*)(lh + off);
                bl[nf] = *(const short8*)(ll + off);
            }
            #pragma unroll
            for (int mf = 0; mf < 4; ++mf)
                #pragma unroll
                for (int nf = 0; nf < 2; ++nf) {
                    acc[mf][nf] = __builtin_amdgcn_mfma_f32_16x16x32_bf16(af[mf], bh[nf], acc[mf][nf], 0,0,0);
                    acc[mf][nf] = __builtin_amdgcn_mfma_f32_16x16x32_bf16(af[mf], bl[nf], acc[mf][nf], 0,0,0);
                }
        }
        __syncthreads();
    }

    #pragma unroll
    for (int nf = 0; nf < 2; ++nf) {
        const int ncol = n0 + wc * 32 + nf * 16 + c;
        const float bv = bias[ncol];
        #pragma unroll
        for (int mf = 0; mf < 4; ++mf)
            #pragma unroll
            for (int j = 0; j < 4; ++j) {
                const int m = m0 + wr * 64 + mf * 16 + g * 4 + j;
                out[(size_t)m * 1024 + ncol] = acc[mf][nf][j] + bv;
            }
    }
}

// ---------------------------------------------------------------------------
// Flash attention, 32x32x16 MFMA, lane-local softmax, in-register P via
// cvt_pk + permlane32_swap. 4 waves x 32 q. KV tile 64 keys, dbuf.
// Swizzle S(row) = ((row&7) ^ ((row>>3)&3)) << 4 — separates rows that
// share row&7 (kills the 4-way bank conflict of round 5).
// ---------------------------------------------------------------------------
__global__ __launch_bounds__(256, 2)
void attn_kernel5(const ushort* __restrict__ Qh, const ushort* __restrict__ Kh,
                  const ushort* __restrict__ Vt, ushort* __restrict__ ctx)
{
    __shared__ __align__(16) ushort KV[2][8192];   // 2 x 16KB (K 8KB | V 8KB)

    const int t  = threadIdx.x, wv = t >> 6, lane = t & 63;
    const int q  = lane & 31;
    const int hi = lane >> 5;
    const int bh = blockIdx.y;
    const int q0 = blockIdx.x * 128 + wv * 32;

    const ushort* Kb = Kh + (size_t)bh * S_LEN * DK;
    const ushort* Vb = Vt + (size_t)bh * DK * S_LEN;
    const ushort* Qb = Qh + ((size_t)bh * S_LEN + q0 + q) * DK;

    short8 qf[4];
    #pragma unroll
    for (int s = 0; s < 4; ++s)
        qf[s] = *(const short8*)(Qb + s * 16 + hi * 8);

    // ---- staging src/dst precompute (k0-invariant) ----
    const ushort* sbase[4];
    int sstr[4];
    char* dbase[4];
    #pragma unroll
    for (int j = 0; j < 4; ++j) {
        const int D = (j * 256 + t) * 16;
        dbase[j] = (char*)&KV[0][0] + D;
        if (D < 8192) {                        // K: row = key, 128B rows
            const int row = D >> 7;
            const int X   = D & 127;
            const int Xs  = X ^ ((((row & 7) ^ ((row >> 3) & 3))) << 4);
            sbase[j] = Kb + row * DK + (Xs >> 1);
            sstr[j]  = DK;
        } else {                               // V: group kk, row r
            const int Y   = D - 8192;
            const int kk  = Y >> 12;
            const int Z   = Y & 4095;
            const int r   = Z >> 7;
            const int gsl = ((Z & 127) >> 4) ^ ((r & 7) ^ ((r >> 3) & 3));
            const int d   = r + ((gsl >> 2) << 5);
            sbase[j] = Vb + (size_t)d * S_LEN + kk * 32 + (gsl & 3) * 8;
            sstr[j]  = 1;
        }
    }
    auto stage = [&](int buf, int k0) {
        #pragma unroll
        for (int j = 0; j < 4; ++j)
            gl_lds16(sbase[j] + (size_t)k0 * sstr[j], dbase[j] + buf * 16384);
    };

    float m = -3.0e38f, l = 0.f;
    f32x16 accO[2];
    #pragma unroll
    for (int i = 0; i < 16; ++i) { accO[0][i] = 0.f; accO[1][i] = 0.f; }

    const int swz = ((q & 7) ^ ((q >> 3) & 3)) << 4;

    stage(0, 0);
    __syncthreads();

    for (int kt = 0; kt < 32; ++kt) {
        const int cur = kt & 1;
        if (kt < 31) stage(cur ^ 1, (kt + 1) * 64);

        const char* Kl = (const char*)&KV[cur][0];
        const char* Vl = Kl + 8192;

        #pragma unroll
        for (int kk = 0; kk < 2; ++kk) {
            // ---- S^T = K (A) x Q^T (B) ----
            f32x16 sa;
            #pragma unroll
            for (int i = 0; i < 16; ++i) sa[i] = 0.f;
            #pragma unroll
            for (int s = 0; s < 4; ++s) {
                short8 kf = *(const short8*)(Kl + (kk * 32 + q) * 128 +
                                             ((s * 32 + hi * 16) ^ swz));
                sa = __builtin_amdgcn_mfma_f32_32x32x16_bf16(kf, qf[s], sa, 0, 0, 0);
            }

            // ---- lane-local max (max3 tree) + cross-half ----
            float m0_ = max3f(sa[0],  sa[1],  sa[2]);
            float m1_ = max3f(sa[3],  sa[4],  sa[5]);
            float m2_ = max3f(sa[6],  sa[7],  sa[8]);
            float m3_ = max3f(sa[9],  sa[10], sa[11]);
            float m4_ = max3f(sa[12], sa[13], sa[14]);
            float mt  = fmaxf(max3f(m0_, m1_, m2_), max3f(m3_, m4_, sa[15]));
            mt = fmaxf(mt, __shfl_xor(mt, 32));

            // ---- defer-max rescale ----
            if (__any(mt > m + 8.f)) {
                const float mnew = fmaxf(m, mt);
                const float corr = __builtin_amdgcn_exp2f(m - mnew);
                #pragma unroll
                for (int r = 0; r < 16; ++r) { accO[0][r] *= corr; accO[1][r] *= corr; }
                l *= corr;
                m = mnew;
            }

            // ---- P = exp2(s - m), lane-local sum ----
            float p[16], ps = 0.f;
            #pragma unroll
            for (int r = 0; r < 16; ++r) {
                p[r] = __builtin_amdgcn_exp2f(sa[r] - m);
                ps += p[r];
            }
            ps += __shfl_xor(ps, 32);
            l += ps;

            // ---- pack + permlane -> PV B-fragments ----
            uint32_t u[8];
            #pragma unroll
            for (int jj = 0; jj < 8; ++jj)
                asm("v_cvt_pk_bf16_f32 %0, %1, %2"
                    : "=v"(u[jj]) : "v"(p[2*jj]), "v"(p[2*jj+1]));
            asm("v_permlane32_swap_b32 %0, %1" : "+v"(u[0]), "+v"(u[2]));
            asm("v_permlane32_swap_b32 %0, %1" : "+v"(u[1]), "+v"(u[3]));
            asm("v_permlane32_swap_b32 %0, %1" : "+v"(u[4]), "+v"(u[6]));
            asm("v_permlane32_swap_b32 %0, %1" : "+v"(u[5]), "+v"(u[7]));
            union { uint32_t w[4]; short8 s8; } pb0, pb1;
            pb0.w[0]=u[0]; pb0.w[1]=u[1]; pb0.w[2]=u[2]; pb0.w[3]=u[3];
            pb1.w[0]=u[4]; pb1.w[1]=u[5]; pb1.w[2]=u[6]; pb1.w[3]=u[7];

            // ---- PV: O^T[d][q] += V^T (A) x P (B) ----
            const char* Vg = Vl + kk * 4096;
            #pragma unroll
            for (int db = 0; db < 2; ++db) {
                short8 vf0 = *(const short8*)(Vg + q * 128 + ((db*64 +      hi*16) ^ swz));
                short8 vf1 = *(const short8*)(Vg + q * 128 + ((db*64 + 32 + hi*16) ^ swz));
                accO[db] = __builtin_amdgcn_mfma_f32_32x32x16_bf16(vf0, pb0.s8, accO[db], 0, 0, 0);
                accO[db] = __builtin_amdgcn_mfma_f32_32x32x16_bf16(vf1, pb1.s8, accO[db], 0, 0, 0);
            }
        }
        __syncthreads();
    }

    // ---- epilogue: /l, scatter plain bf16 ----
    const float inv = 1.f / l;
    const int b = bh >> 4, h = bh & 15;
    ushort* base = ctx + ((size_t)b * S_LEN + q0 + q) * DMODEL + h * DK;
    #pragma unroll
    for (int db = 0; db < 2; ++db)
        #pragma unroll
        for (int r = 0; r < 16; ++r) {
            const int d = db * 32 + (r & 3) + 8 * (r >> 2) + 4 * hi;
            base[d] = f2bf(accO[db][r] * inv);
        }
}

// ---------------------------------------------------------------------------
extern "C" void kernel_launch(void* const* d_in, const int* in_sizes, int n_in,
                              void* d_out, int out_size, void* d_ws, size_t ws_size,
                              hipStream_t stream)
{
    const float* query  = (const float*)d_in[0];
    const float* key_in = (const float*)d_in[1];
    const float* value  = (const float*)d_in[2];
    const float* w_q = (const float*)d_in[3];
    const float* b_q = (const float*)d_in[4];
    const float* w_k = (const float*)d_in[5];
    const float* b_k = (const float*)d_in[6];
    const float* w_v = (const float*)d_in[7];
    const float* b_v = (const float*)d_in[8];
    const float* w_o = (const float*)d_in[9];
    const float* b_o = (const float*)d_in[10];
    float* out = (float*)d_out;

    const size_t E4M = (size_t)M_TOT * DMODEL;
    const size_t E1M = (size_t)DMODEL * DMODEL;

    ushort* ws = (ushort*)d_ws;
    ushort* Aq    = ws;                // later reused as ctx
    ushort* Ak    = Aq + E4M;
    ushort* Av    = Ak + E4M;
    ushort* Qh    = Av + E4M;
    ushort* Kh    = Qh + E4M;
    ushort* Vt    = Kh + E4M;
    ushort* Wq    = Vt + E4M;
    ushort* Wk    = Wq + E1M;
    ushort* Wv    = Wk + E1M;
    ushort* Wo_hi = Wv + E1M;
    ushort* Wo_lo = Wo_hi + E1M;
    ushort* ctx   = Aq;

    const float qscale = 0.125f * 1.44269504088896340736f;

    dim3 blk(256);
    hipLaunchKernelGGL(conv3_kernel, dim3(512, 1, 3), blk, 0, stream,
                       query, key_in, value, Aq, Ak, Av, (int)(E4M / 8));
    hipLaunchKernelGGL(wtrans4_kernel, dim3(16, 16, 4), blk, 0, stream,
                       w_q, w_k, w_v, w_o, Wq, Wk, Wv, Wo_hi, Wo_lo);

    dim3 ggrd(DMODEL / 64, M_TOT / 128, 3);
    hipLaunchKernelGGL(gemm_qkv_kernel, ggrd, blk, 0, stream,
                       Aq, Ak, Av, Wq, Wk, Wv, b_q, b_k, b_v, Qh, Kh, Vt, qscale);

    dim3 agrd(S_LEN / 128, BATCH * NHEADS);
    hipLaunchKernelGGL(attn_kernel5, agrd, blk, 0, stream, Qh, Kh, Vt, ctx);

    dim3 ogrd(DMODEL / 64, M_TOT / 128);
    hipLaunchKernelGGL(gemm_o2_kernel, ogrd, blk, 0, stream,
                       ctx, Wo_hi, Wo_lo, b_o, out);
}